// Round 7
// baseline (2131.383 us; speedup 1.0000x reference)
//
#include <hip/hip_runtime.h>
#include <hip/hip_bf16.h>
#include <cstdint>

#define DEV __device__ __forceinline__

// Problem constants (from setup_inputs)
constexpr int Bn   = 8;
constexpr int Nn   = 4096;
constexpr int Mn   = 1024;   // N / STRIDE
constexpr int Kn   = 32;     // NSAMPLE
constexpr int CIN  = 64;
constexpr int COUT = 128;

// ---------------------------------------------------------------------------
// feats (B, 64, 4096) -> featsT (B, 4096, 64)
// ---------------------------------------------------------------------------
__global__ __launch_bounds__(256) void k_tr(const float* __restrict__ feats,
                                            float* __restrict__ featsT) {
  __shared__ float tile[64][65];
  int b = blockIdx.x >> 6, n0 = (blockIdx.x & 63) * 64;
  int t = threadIdx.x;
  int lane = t & 63, grp = t >> 6;
  for (int r = 0; r < 16; ++r) {
    int c = grp + r * 4;
    tile[c][lane] = feats[((size_t)b * 64 + c) * 4096 + n0 + lane];
  }
  __syncthreads();
  for (int r = 0; r < 16; ++r) {
    int n = grp + r * 4;
    featsT[((size_t)b * 4096 + n0 + n) * 64 + lane] = tile[lane][n];
  }
}

// ---------------------------------------------------------------------------
// FPS v5: exact bucket-pruned. 1 block/batch, 512 threads (8 waves).
// Morton counting-sort (12-bit) once in LDS -> thread owns 8 coherent points
// with bounding sphere (center, rad + 1e-3 margin) + cached bucket-max key.
// Per iter: skip bucket update iff D^2(far,center) >= (sqrt(lmax)+rad)^2
// (triangle inequality => exact). Wave with all lanes skipped reuses cached
// reduced key (no DPP). Keys (valbits<<24)|(4095-oidx)<<12|spos preserve the
// reference's (max value, min orig index) decision bit-exactly; update
// arithmetic = proven __f*_rn sequence.
// ---------------------------------------------------------------------------
DEV unsigned long long wave_max_key(unsigned long long key) {
#if __has_builtin(__builtin_amdgcn_update_dpp)
#define DPP_STEP(CTRL, RMASK)                                                          \
  {                                                                                    \
    unsigned int lo2 = (unsigned int)__builtin_amdgcn_update_dpp(                      \
        0, (int)(unsigned int)key, CTRL, RMASK, 0xf, false);                           \
    unsigned int hi2 = (unsigned int)__builtin_amdgcn_update_dpp(                      \
        0, (int)(unsigned int)(key >> 32), CTRL, RMASK, 0xf, false);                   \
    unsigned long long k2 = ((unsigned long long)hi2 << 32) | lo2;                     \
    if (k2 > key) key = k2;                                                            \
  }
  DPP_STEP(0x111, 0xf)  // row_shr:1
  DPP_STEP(0x112, 0xf)  // row_shr:2
  DPP_STEP(0x114, 0xf)  // row_shr:4
  DPP_STEP(0x118, 0xf)  // row_shr:8
  DPP_STEP(0x142, 0xa)  // row_bcast:15 rows 1,3
  DPP_STEP(0x143, 0xc)  // row_bcast:31 rows 2,3
#undef DPP_STEP
#else
  for (int off = 1; off < 64; off <<= 1) {
    unsigned int lo2 = __shfl_xor((unsigned int)key, off, 64);
    unsigned int hi2 = __shfl_xor((unsigned int)(key >> 32), off, 64);
    unsigned long long k2 = ((unsigned long long)hi2 << 32) | lo2;
    if (k2 > key) key = k2;
  }
#endif
  return key;  // lane 63 holds the wave max
}

DEV unsigned long long wave_reduce_bcast(unsigned long long key) {
  key = wave_max_key(key);
  unsigned int lo = (unsigned int)__builtin_amdgcn_readlane((int)(unsigned int)key, 63);
  unsigned int hi = (unsigned int)__builtin_amdgcn_readlane((int)(unsigned int)(key >> 32), 63);
  return ((unsigned long long)hi << 32) | lo;
}

DEV unsigned long long grp8_max_u64(unsigned long long k) {
#if __has_builtin(__builtin_amdgcn_update_dpp)
#define USTEP(CTRL)                                                                    \
  {                                                                                    \
    unsigned int lo = (unsigned int)__builtin_amdgcn_update_dpp(                       \
        0, (int)(unsigned int)k, CTRL, 0xf, 0xf, false);                               \
    unsigned int hi = (unsigned int)__builtin_amdgcn_update_dpp(                       \
        0, (int)(unsigned int)(k >> 32), CTRL, 0xf, 0xf, false);                       \
    unsigned long long o = ((unsigned long long)hi << 32) | lo;                        \
    if (o > k) k = o;                                                                  \
  }
  USTEP(0x111)  // row_shr:1
  USTEP(0x112)  // row_shr:2
  USTEP(0x114)  // row_shr:4
#undef USTEP
#else
  for (int off = 1; off < 8; off <<= 1) {
    unsigned int lo = __shfl_xor((unsigned int)k, off, 64);
    unsigned int hi = __shfl_xor((unsigned int)(k >> 32), off, 64);
    unsigned long long o = ((unsigned long long)hi << 32) | lo;
    if (o > k) k = o;
  }
#endif
  return k;  // lane 7 of each row holds max of that row's lanes 0..7
}

// local argmax over 8 (value, orig-index) pairs; tie -> min orig index
DEV void tree8_idx(const float v[8], const int oid[8], int sbase,
                   float& bv, int& bo, int& bs) {
  float v4[4]; int o4[4], s4[4];
#pragma unroll
  for (int i = 0; i < 4; ++i) {
    int a = 2 * i, c = 2 * i + 1;
    bool r = (v[c] > v[a]) || (v[c] == v[a] && oid[c] < oid[a]);
    v4[i] = r ? v[c] : v[a]; o4[i] = r ? oid[c] : oid[a]; s4[i] = sbase + (r ? c : a);
  }
  float v2[2]; int o2[2], s2[2];
#pragma unroll
  for (int i = 0; i < 2; ++i) {
    int a = 2 * i, c = 2 * i + 1;
    bool r = (v4[c] > v4[a]) || (v4[c] == v4[a] && o4[c] < o4[a]);
    v2[i] = r ? v4[c] : v4[a]; o2[i] = r ? o4[c] : o4[a]; s2[i] = r ? s4[c] : s4[a];
  }
  bool r = (v2[1] > v2[0]) || (v2[1] == v2[0] && o2[1] < o2[0]);
  bv = r ? v2[1] : v2[0]; bo = r ? o2[1] : o2[0]; bs = r ? s2[1] : s2[0];
}

DEV int expand3(int v) {  // 4 bits -> every 3rd bit
  return (v & 1) | ((v & 2) << 2) | ((v & 4) << 4) | ((v & 8) << 6);
}
DEV int mcode(float x, float y, float z) {
  int ix = min(15, max(0, (int)(x * 16.f)));
  int iy = min(15, max(0, (int)(y * 16.f)));
  int iz = min(15, max(0, (int)(z * 16.f)));
  return expand3(ix) | (expand3(iy) << 1) | (expand3(iz) << 2);
}

DEV unsigned long long pack_key(float bv, int bo, int bs) {
  return ((unsigned long long)__float_as_uint(bv) << 24) |
         ((unsigned long long)(4095 - bo) << 12) | (unsigned long long)bs;
}

__global__ __launch_bounds__(512, 1) void k_fps(const float* __restrict__ coords,
                                                uint32_t* __restrict__ sidx,
                                                float* __restrict__ outc) {
  const int b = blockIdx.x, t = threadIdx.x;
  __shared__ float4 spA[Nn];       // orig order (64 KB)
  __shared__ float4 spS[Nn];       // Morton order, .w = orig idx bits (64 KB)
  __shared__ int    hist[Nn];      // 16 KB
  __shared__ unsigned long long part[2][8];
  __shared__ uint32_t farl[Mn];    // scan scratch, then results (4 KB)
  __shared__ float s_mean[4];

  const float* cb = coords + (size_t)b * Nn * 3;
  for (int i = t; i < Nn; i += 512)
    spA[i] = make_float4(cb[3 * i], cb[3 * i + 1], cb[3 * i + 2], 0.f);
  for (int i = t; i < Nn; i += 512) hist[i] = 0;
  __syncthreads();
  // histogram (all threads) + sequential in-order fp32 mean (t0, proven R1-R6)
  for (int i = t; i < Nn; i += 512) {
    float4 c = spA[i];
    atomicAdd(&hist[mcode(c.x, c.y, c.z)], 1);
  }
  if (t == 0) {
    float ax = 0.f, ay = 0.f, az = 0.f;
    for (int i = 0; i < Nn; ++i) {
      float4 c = spA[i];
      ax = __fadd_rn(ax, c.x); ay = __fadd_rn(ay, c.y); az = __fadd_rn(az, c.z);
    }
    s_mean[0] = __fdiv_rn(ax, 4096.f);
    s_mean[1] = __fdiv_rn(ay, 4096.f);
    s_mean[2] = __fdiv_rn(az, 4096.f);
  }
  __syncthreads();
  // exclusive scan of hist (4096 cells): per-thread 8 + serial 512 + fixup
  int lc[8]; int lsum = 0;
#pragma unroll
  for (int j = 0; j < 8; ++j) { lc[j] = hist[8 * t + j]; lsum += lc[j]; }
  farl[t] = (uint32_t)lsum;
  __syncthreads();
  if (t == 0) {
    int run = 0;
    for (int j = 0; j < 512; ++j) { int v = (int)farl[j]; farl[j] = (uint32_t)run; run += v; }
  }
  __syncthreads();
  {
    int base = (int)farl[t];
#pragma unroll
    for (int j = 0; j < 8; ++j) { hist[8 * t + j] = base; base += lc[j]; }
  }
  __syncthreads();
  // scatter into Morton order (intra-cell order nondeterministic -> only
  // affects bucket composition / perf, never the selected indices)
  for (int i = t; i < Nn; i += 512) {
    float4 c = spA[i];
    int pos = atomicAdd(&hist[mcode(c.x, c.y, c.z)], 1);
    spS[pos] = make_float4(c.x, c.y, c.z, __int_as_float(i));
  }
  __syncthreads();

  // per-thread bucket of 8 sorted points
  float px[8], py[8], pz[8], md[8]; int oid[8];
#pragma unroll
  for (int j = 0; j < 8; ++j) {
    float4 c = spS[8 * t + j];
    px[j] = c.x; py[j] = c.y; pz[j] = c.z;
    oid[j] = __float_as_int(c.w);
    md[j] = __builtin_inff();
  }
  float bcx = 0.f, bcy = 0.f, bcz = 0.f;
#pragma unroll
  for (int j = 0; j < 8; ++j) { bcx += px[j]; bcy += py[j]; bcz += pz[j]; }
  bcx *= 0.125f; bcy *= 0.125f; bcz *= 0.125f;
  float rr = 0.f;
#pragma unroll
  for (int j = 0; j < 8; ++j) {
    float dx = px[j] - bcx, dy = py[j] - bcy, dz = pz[j] - bcz;
    rr = fmaxf(rr, dx * dx + dy * dy + dz * dz);
  }
  const float rad = sqrtf(rr) * 1.0001f + 1e-3f;   // conservative margin
  float s_skip = __builtin_inff();                  // never skip until md finite
  unsigned long long ckey, wkey;

  // round 0: argmax dist-to-mean (full compute)
  uint32_t lo_win;
  {
    float mx = s_mean[0], my = s_mean[1], mz = s_mean[2];
    float tv[8];
#pragma unroll
    for (int j = 0; j < 8; ++j) {
      float dx = __fsub_rn(px[j], mx), dy = __fsub_rn(py[j], my), dz = __fsub_rn(pz[j], mz);
      tv[j] = __fadd_rn(__fadd_rn(__fmul_rn(dx, dx), __fmul_rn(dy, dy)), __fmul_rn(dz, dz));
    }
    float bv; int bo, bs;
    tree8_idx(tv, oid, 8 * t, bv, bo, bs);
    ckey = pack_key(bv, bo, bs);
    wkey = wave_reduce_bcast(ckey);
    if ((t & 63) == 0) part[0][t >> 6] = wkey;
    __syncthreads();
    unsigned long long kk = part[0][t & 7];
    kk = grp8_max_u64(kk);
    lo_win = (uint32_t)__builtin_amdgcn_readlane((int)(unsigned int)kk, 7);
  }

  for (int p = 1; p < Mn; ++p) {
    if (t == 0)
      farl[p - 1] = (4095u - ((lo_win >> 12) & 4095u)) | ((lo_win & 4095u) << 12);
    float4 c = spS[lo_win & 4095u];  // broadcast read of the new center
    float dxc = c.x - bcx, dyc = c.y - bcy, dzc = c.z - bcz;
    float D2 = dxc * dxc + dyc * dyc + dzc * dzc;
    bool upd = (D2 < s_skip);
    if (__any((int)upd)) {
      if (upd) {
#pragma unroll
        for (int j = 0; j < 8; ++j) {
          float dx = __fsub_rn(px[j], c.x), dy = __fsub_rn(py[j], c.y), dz = __fsub_rn(pz[j], c.z);
          float d = __fadd_rn(__fadd_rn(__fmul_rn(dx, dx), __fmul_rn(dy, dy)), __fmul_rn(dz, dz));
          md[j] = fminf(md[j], d);
        }
        float bv; int bo, bs;
        tree8_idx(md, oid, 8 * t, bv, bo, bs);
        ckey = pack_key(bv, bo, bs);
        float sv = sqrtf(bv) + rad;
        s_skip = sv * sv;
      }
      wkey = wave_reduce_bcast(ckey);
    }
    const int sl = p & 1;
    if ((t & 63) == 0) part[sl][t >> 6] = wkey;
    __syncthreads();
    unsigned long long kk = part[sl][t & 7];
    kk = grp8_max_u64(kk);
    lo_win = (uint32_t)__builtin_amdgcn_readlane((int)(unsigned int)kk, 7);
  }
  if (t == 0)
    farl[Mn - 1] = (4095u - ((lo_win >> 12) & 4095u)) | ((lo_win & 4095u) << 12);
  __syncthreads();

  for (int i = t; i < Mn; i += 512) {
    uint32_t f = farl[i];
    uint32_t oidx = f & 4095u, spos = (f >> 12) & 4095u;
    sidx[b * Mn + i] = oidx;
    float4 c = spS[spos];
    outc[(size_t)(b * Mn + i) * 3 + 0] = c.x;
    outc[(size_t)(b * Mn + i) * 3 + 1] = c.y;
    outc[(size_t)(b * Mn + i) * 3 + 2] = c.z;
  }
}

// ---------------------------------------------------------------------------
// 32-NN per query (== reference ball_query+knn fallback) + density weights.
// Compact within-radius candidates, rank-select 32 smallest (d2,idx) keys.
// Radius expansion 0.04 -> 0.16 -> inf if fewer than 32 candidates.
// ---------------------------------------------------------------------------
__global__ __launch_bounds__(256) void k_knn(const float* __restrict__ coords,
                                             const uint32_t* __restrict__ sidx,
                                             uint32_t* __restrict__ gidx,
                                             float* __restrict__ wts) {
  const int q = blockIdx.x;
  const int b = q >> 10;
  const int t = threadIdx.x;
  __shared__ unsigned long long keys[Nn + 2];
  __shared__ int s_cnt;
  __shared__ float s_q[4];
  __shared__ uint32_t s_sel[32];
  __shared__ float gx[32], gy[32], gz[32], g2[32];
  __shared__ float dmat[32 * 33];
  __shared__ float kth[32];
  __shared__ float s_raw[32];
  __shared__ float s_sum;

  if (t == 0) {
    uint32_t si = sidx[q];
    const float* c = &coords[((size_t)b * Nn + si) * 3];
    s_q[0] = c[0]; s_q[1] = c[1]; s_q[2] = c[2];
  }
  __syncthreads();
  float qx = s_q[0], qy = s_q[1], qz = s_q[2];
  float q2 = __fadd_rn(__fadd_rn(__fmul_rn(qx, qx), __fmul_rn(qy, qy)), __fmul_rn(qz, qz));
  const float* cb = coords + (size_t)b * Nn * 3;

  float thr = 0.04f;
  int cnt = 0;
  while (true) {
    if (t == 0) s_cnt = 0;
    __syncthreads();
    for (int j = 0; j < 16; ++j) {
      int i = t + 256 * j;
      float cx = cb[3 * i], cy = cb[3 * i + 1], cz = cb[3 * i + 2];
      float c2  = __fadd_rn(__fadd_rn(__fmul_rn(cx, cx), __fmul_rn(cy, cy)), __fmul_rn(cz, cz));
      float dot = __fadd_rn(__fadd_rn(__fmul_rn(qx, cx), __fmul_rn(qy, cy)), __fmul_rn(qz, cz));
      float d2  = __fsub_rn(__fadd_rn(q2, c2), __fmul_rn(2.f, dot));
      float d2c = fmaxf(d2, 1e-12f);
      bool pred = (d2c <= thr);
      unsigned long long mk = __ballot(pred);
      int base = 0;
      if ((t & 63) == 0 && mk) base = atomicAdd(&s_cnt, (int)__popcll(mk));
      base = __shfl(base, 0, 64);
      if (pred) {
        int pos = base + (int)__popcll(mk & ((1ull << (t & 63)) - 1ull));
        keys[pos] = ((unsigned long long)__float_as_uint(d2c) << 32) | (uint32_t)i;
      }
    }
    __syncthreads();
    cnt = s_cnt;
    if (cnt >= 32 || thr > 1.f) break;
    thr = (thr < 0.1f) ? 0.16f : 8.f;
    __syncthreads();
  }
  if (t == 0) { keys[cnt] = ~0ull; keys[cnt + 1] = ~0ull; }
  __syncthreads();
  int cnt2 = (cnt + 1) & ~1;
  for (int i = t; i < cnt; i += 256) {
    unsigned long long ki = keys[i];
    int r = 0;
    for (int j2 = 0; j2 < cnt2; j2 += 2) {
      unsigned long long a = keys[j2], c2 = keys[j2 + 1];
      r += (a < ki) + (c2 < ki);
    }
    if (r < 32) s_sel[r] = (uint32_t)ki;
  }
  __syncthreads();

  if (t < 32) {
    uint32_t gi = s_sel[t];
    gidx[(size_t)q * 32 + t] = gi;
    const float* c = &coords[((size_t)b * Nn + gi) * 3];
    float x = c[0], y = c[1], z = c[2];
    gx[t] = x; gy[t] = y; gz[t] = z;
    g2[t] = __fadd_rn(__fadd_rn(__fmul_rn(x, x), __fmul_rn(y, y)), __fmul_rn(z, z));
  }
  __syncthreads();
  for (int p = t; p < 1024; p += 256) {
    int i = p >> 5, jj = p & 31;
    float dot = __fadd_rn(__fadd_rn(__fmul_rn(gx[i], gx[jj]), __fmul_rn(gy[i], gy[jj])),
                          __fmul_rn(gz[i], gz[jj]));
    float d2 = __fsub_rn(__fadd_rn(g2[i], g2[jj]), __fmul_rn(2.f, dot));
    float dd = sqrtf(fmaxf(d2, 1e-12f));
    if (i == jj) dd = __builtin_inff();
    dmat[i * 33 + jj] = dd;
  }
  __syncthreads();
  for (int p = t; p < 1024; p += 256) {
    int i = p >> 5, jj = p & 31;
    float v = dmat[i * 33 + jj];
    int r = 0;
    for (int c = 0; c < 32; ++c) {
      float u = dmat[i * 33 + c];
      r += (u < v) || (u == v && c < jj);
    }
    if (r == 15) kth[i] = v;
  }
  __syncthreads();
  if (t < 32) { float x = fmaxf(kth[t], 1e-8f); s_raw[t] = x * x * x; }
  __syncthreads();
  if (t == 0) {
    float s = 0.f;
    for (int i2 = 0; i2 < 32; ++i2) s += s_raw[i2];
    s_sum = fmaxf(s, 1e-8f);
  }
  __syncthreads();
  if (t < 32) wts[(size_t)q * 32 + t] = s_raw[t] / s_sum;
}

// ---------------------------------------------------------------------------
// Conv pipeline. Tile = 4 queries x 32 neighbors (GEMM k-dim = 128).
// Thread tile: 4 outputs x 8 k (o0 = (t&15)*4, k0 = (t>>4)*8).
// LDS: xs[67][132] (row 0..2 = rel, 3..66 = feats), w0sT[67][68] (W0^T).
// ---------------------------------------------------------------------------
constexpr int XST = 132;
constexpr int WST = 68;

DEV void build_x(const float* __restrict__ coords, const float* __restrict__ featsT,
                 const uint32_t* __restrict__ sidx, const uint32_t* __restrict__ gidx,
                 const float* __restrict__ W0, int b, int m0, int t,
                 float* xs, float* w0sT, uint32_t* s_gi, float* s_qc) {
  for (int i = t; i < 64 * 67; i += 256) {
    int o = i / 67, c = i - o * 67;
    w0sT[c * WST + o] = W0[i];
  }
  if (t < 128) {
    s_gi[t] = gidx[((size_t)(b * Mn + m0)) * 32 + t];
  } else if (t < 132) {
    int mm = t - 128;
    uint32_t si = sidx[b * Mn + m0 + mm];
    const float* c = &coords[((size_t)b * Nn + si) * 3];
    s_qc[mm * 3 + 0] = c[0]; s_qc[mm * 3 + 1] = c[1]; s_qc[mm * 3 + 2] = c[2];
  }
  __syncthreads();
  if (t < 128) {
    int mm = t >> 5;
    const float* c = &coords[((size_t)b * Nn + s_gi[t]) * 3];
    xs[0 * XST + t] = (c[0] - s_qc[mm * 3 + 0]) / 0.2f;
    xs[1 * XST + t] = (c[1] - s_qc[mm * 3 + 1]) / 0.2f;
    xs[2 * XST + t] = (c[2] - s_qc[mm * 3 + 2]) / 0.2f;
  }
  {
    int c = t & 63, k0g = t >> 6;
    for (int r2 = 0; r2 < 32; ++r2) {
      int kk = k0g + 4 * r2;
      xs[(size_t)(3 + c) * XST + kk] = featsT[((size_t)b * Nn + s_gi[kk]) * 64 + c];
    }
  }
  __syncthreads();
}

DEV void conv1_acc(const float* xs, const float* w0sT, int o0, int k0, float acc[32]) {
#pragma unroll
  for (int i = 0; i < 32; ++i) acc[i] = 0.f;
  for (int c = 0; c < 67; ++c) {
    float4 w  = *(const float4*)&w0sT[c * WST + o0];
    float4 xa = *(const float4*)&xs[c * XST + k0];
    float4 xb = *(const float4*)&xs[c * XST + k0 + 4];
    float wv[4] = {w.x, w.y, w.z, w.w};
    float xv[8] = {xa.x, xa.y, xa.z, xa.w, xb.x, xb.y, xb.z, xb.w};
#pragma unroll
    for (int i = 0; i < 4; ++i)
#pragma unroll
      for (int j = 0; j < 8; ++j)
        acc[i * 8 + j] = fmaf(wv[i], xv[j], acc[i * 8 + j]);
  }
}

DEV void conv2_acc(const float* hs, const float* w1sT, int o0, int k0, float acc2[32]) {
#pragma unroll
  for (int i = 0; i < 32; ++i) acc2[i] = 0.f;
  for (int c = 0; c < 64; ++c) {
    float4 w  = *(const float4*)&w1sT[c * WST + o0];
    float4 xa = *(const float4*)&hs[c * XST + k0];
    float4 xb = *(const float4*)&hs[c * XST + k0 + 4];
    float wv[4] = {w.x, w.y, w.z, w.w};
    float xv[8] = {xa.x, xa.y, xa.z, xa.w, xb.x, xb.y, xb.z, xb.w};
#pragma unroll
    for (int i = 0; i < 4; ++i)
#pragma unroll
      for (int j = 0; j < 8; ++j)
        acc2[i * 8 + j] = fmaf(wv[i], xv[j], acc2[i * 8 + j]);
  }
}

// stats layout (floats): [0,64) s0 | [64,128) q0 | [128,256) s1 | [256,384) q1
// | [384,512) ss | [512,640) qs | 640 a0 | 704 c0 | 768 a1 | 896 c1
// | 1024 as | 1152 cs
__global__ __launch_bounds__(256) void k_conv1(const float* __restrict__ coords,
                                               const float* __restrict__ featsT,
                                               const uint32_t* __restrict__ sidx,
                                               const uint32_t* __restrict__ gidx,
                                               const float* __restrict__ W0,
                                               float* __restrict__ stats) {
  __shared__ float xs[67 * XST];
  __shared__ float w0sT[67 * WST];
  __shared__ uint32_t s_gi[128];
  __shared__ float s_qc[12];
  __shared__ float ssum[64], ssq[64];
  int blk = blockIdx.x, t = threadIdx.x;
  int b = blk >> 8, m0 = (blk & 255) << 2;
  if (t < 64) { ssum[t] = 0.f; ssq[t] = 0.f; }
  build_x(coords, featsT, sidx, gidx, W0, b, m0, t, xs, w0sT, s_gi, s_qc);
  int o0 = (t & 15) * 4, k0 = (t >> 4) * 8;
  float acc[32];
  conv1_acc(xs, w0sT, o0, k0, acc);
#pragma unroll
  for (int i = 0; i < 4; ++i) {
    float s = 0.f, sq = 0.f;
#pragma unroll
    for (int j = 0; j < 8; ++j) { s += acc[i * 8 + j]; sq = fmaf(acc[i * 8 + j], acc[i * 8 + j], sq); }
    atomicAdd(&ssum[o0 + i], s); atomicAdd(&ssq[o0 + i], sq);
  }
  __syncthreads();
  if (t < 64) { atomicAdd(&stats[t], ssum[t]); atomicAdd(&stats[64 + t], ssq[t]); }
}

__global__ void k_fin0(float* stats, const float* g0, const float* b0) {
  int t = threadIdx.x;
  if (t >= 64) return;
  float mu  = stats[t] * (1.f / 262144.f);
  float var = stats[64 + t] * (1.f / 262144.f) - mu * mu;
  float a = g0[t] / sqrtf(var + 1e-5f);
  stats[640 + t] = a;
  stats[704 + t] = b0[t] - mu * a;
}

__global__ __launch_bounds__(256) void k_conv2(const float* __restrict__ coords,
                                               const float* __restrict__ featsT,
                                               const uint32_t* __restrict__ sidx,
                                               const uint32_t* __restrict__ gidx,
                                               const float* __restrict__ W0,
                                               const float* __restrict__ W1,
                                               float* __restrict__ stats) {
  __shared__ float smU[13400];  // xs+w0sT (8844+4556) | hs+w1sT (8448+4352)
  __shared__ uint32_t s_gi[128];
  __shared__ float s_qc[12];
  __shared__ float ssum[128], ssq[128];
  float* xs = smU;  float* w0sT = smU + 67 * XST;
  float* hs = smU;  float* w1sT = smU + 64 * XST;
  int blk = blockIdx.x, t = threadIdx.x;
  int b = blk >> 8, m0 = (blk & 255) << 2;
  if (t < 128) { ssum[t] = 0.f; ssq[t] = 0.f; }
  build_x(coords, featsT, sidx, gidx, W0, b, m0, t, xs, w0sT, s_gi, s_qc);
  int o0 = (t & 15) * 4, k0 = (t >> 4) * 8;
  float acc[32];
  conv1_acc(xs, w0sT, o0, k0, acc);
  float4 a04 = *(const float4*)&stats[640 + o0];
  float4 c04 = *(const float4*)&stats[704 + o0];
  float a0v[4] = {a04.x, a04.y, a04.z, a04.w};
  float c0v[4] = {c04.x, c04.y, c04.z, c04.w};
  __syncthreads();  // all conv1 LDS reads complete; smU repurposed
#pragma unroll
  for (int i = 0; i < 4; ++i) {
    float h[8];
#pragma unroll
    for (int j = 0; j < 8; ++j) h[j] = fmaxf(fmaf(a0v[i], acc[i * 8 + j], c0v[i]), 0.f);
    *(float4*)&hs[(o0 + i) * XST + k0]     = make_float4(h[0], h[1], h[2], h[3]);
    *(float4*)&hs[(o0 + i) * XST + k0 + 4] = make_float4(h[4], h[5], h[6], h[7]);
  }
  for (int p = 0; p < 2; ++p) {
    __syncthreads();
    for (int i = t; i < 64 * 64; i += 256) {
      int oo = i >> 6, cc = i & 63;
      w1sT[cc * WST + oo] = W1[(size_t)(64 * p + oo) * 64 + cc];
    }
    __syncthreads();
    float acc2[32];
    conv2_acc(hs, w1sT, o0, k0, acc2);
#pragma unroll
    for (int i = 0; i < 4; ++i) {
      float s = 0.f, sq = 0.f;
#pragma unroll
      for (int j = 0; j < 8; ++j) { s += acc2[i * 8 + j]; sq = fmaf(acc2[i * 8 + j], acc2[i * 8 + j], sq); }
      atomicAdd(&ssum[64 * p + o0 + i], s); atomicAdd(&ssq[64 * p + o0 + i], sq);
    }
  }
  __syncthreads();
  if (t < 128) { atomicAdd(&stats[128 + t], ssum[t]); atomicAdd(&stats[256 + t], ssq[t]); }
}

__global__ __launch_bounds__(256) void k_skip(const float* __restrict__ featsT,
                                              const uint32_t* __restrict__ sidx,
                                              const float* __restrict__ Ws,
                                              float* __restrict__ ys,
                                              float* __restrict__ stats) {
  __shared__ float fin[64 * 65];
  __shared__ float wssT[64 * 129];
  __shared__ uint32_t s_si[64];
  __shared__ float ssum[128], ssq[128];
  int blk = blockIdx.x, t = threadIdx.x;
  int b = blk >> 4, m0 = (blk & 15) * 64;
  if (t < 64) s_si[t] = sidx[b * Mn + m0 + t];
  if (t < 128) { ssum[t] = 0.f; ssq[t] = 0.f; }
  __syncthreads();
  for (int i = t; i < 64 * 64; i += 256) {
    int mm = i >> 6, c = i & 63;
    fin[mm * 65 + c] = featsT[((size_t)b * Nn + s_si[mm]) * 64 + c];
  }
  for (int i = t; i < 128 * 64; i += 256) {
    int oo = i >> 6, cc = i & 63;
    wssT[cc * 129 + oo] = Ws[(size_t)oo * 64 + cc];
  }
  __syncthreads();
  int o = t & 127, mh = t >> 7;
  float s = 0.f, sq = 0.f;
  for (int mm = mh * 32; mm < mh * 32 + 32; ++mm) {
    float acc = 0.f;
    for (int c = 0; c < 64; ++c) acc = fmaf(wssT[c * 129 + o], fin[mm * 65 + c], acc);
    ys[((size_t)(b * Mn + m0 + mm)) * 128 + o] = acc;
    s += acc; sq = fmaf(acc, acc, sq);
  }
  atomicAdd(&ssum[o], s); atomicAdd(&ssq[o], sq);
  __syncthreads();
  if (t < 128) { atomicAdd(&stats[384 + t], ssum[t]); atomicAdd(&stats[512 + t], ssq[t]); }
}

__global__ void k_fin1(float* stats, const float* g1, const float* b1,
                       const float* gs, const float* bs) {
  int t = threadIdx.x;
  if (t >= 128) return;
  float mu  = stats[128 + t] * (1.f / 262144.f);
  float var = stats[256 + t] * (1.f / 262144.f) - mu * mu;
  float a = g1[t] / sqrtf(var + 1e-5f);
  stats[768 + t] = a;
  stats[896 + t] = b1[t] - mu * a;
  float mus  = stats[384 + t] * (1.f / 8192.f);
  float vars = stats[512 + t] * (1.f / 8192.f) - mus * mus;
  float as = gs[t] / sqrtf(vars + 1e-5f);
  stats[1024 + t] = as;
  stats[1152 + t] = bs[t] - mus * as;
}

__global__ __launch_bounds__(256) void k_out(const float* __restrict__ coords,
                                             const float* __restrict__ featsT,
                                             const uint32_t* __restrict__ sidx,
                                             const uint32_t* __restrict__ gidx,
                                             const float* __restrict__ W0,
                                             const float* __restrict__ W1,
                                             const float* __restrict__ wts,
                                             const float* __restrict__ ys,
                                             const float* __restrict__ stats,
                                             float* __restrict__ out_feat) {
  __shared__ float smU[13400];
  __shared__ uint32_t s_gi[128];
  __shared__ float s_qc[12];
  __shared__ float sw[4 * 36];
  __shared__ float red[128 * 5];
  float* xs = smU;  float* w0sT = smU + 67 * XST;
  float* hs = smU;  float* w1sT = smU + 64 * XST;
  int blk = blockIdx.x, t = threadIdx.x;
  int b = blk >> 8, m0 = (blk & 255) << 2;
  build_x(coords, featsT, sidx, gidx, W0, b, m0, t, xs, w0sT, s_gi, s_qc);
  if (t < 128) sw[(t >> 5) * 36 + (t & 31)] = wts[((size_t)(b * Mn + m0)) * 32 + t];
  int o0 = (t & 15) * 4, k0 = (t >> 4) * 8;
  int m = k0 >> 5, nb0 = k0 & 31;  // query idx (== wave id), neighbor offset
  float acc[32];
  conv1_acc(xs, w0sT, o0, k0, acc);
  float4 a04 = *(const float4*)&stats[640 + o0];
  float4 c04 = *(const float4*)&stats[704 + o0];
  float a0v[4] = {a04.x, a04.y, a04.z, a04.w};
  float c0v[4] = {c04.x, c04.y, c04.z, c04.w};
  __syncthreads();
#pragma unroll
  for (int i = 0; i < 4; ++i) {
    float h[8];
#pragma unroll
    for (int j = 0; j < 8; ++j) h[j] = fmaxf(fmaf(a0v[i], acc[i * 8 + j], c0v[i]), 0.f);
    *(float4*)&hs[(o0 + i) * XST + k0]     = make_float4(h[0], h[1], h[2], h[3]);
    *(float4*)&hs[(o0 + i) * XST + k0 + 4] = make_float4(h[4], h[5], h[6], h[7]);
  }
  for (int p = 0; p < 2; ++p) {
    __syncthreads();
    for (int i = t; i < 64 * 64; i += 256) {
      int oo = i >> 6, cc = i & 63;
      w1sT[cc * WST + oo] = W1[(size_t)(64 * p + oo) * 64 + cc];
    }
    __syncthreads();
    float acc2[32];
    conv2_acc(hs, w1sT, o0, k0, acc2);
    float4 swa = *(const float4*)&sw[m * 36 + nb0];
    float4 swb = *(const float4*)&sw[m * 36 + nb0 + 4];
    float wv[8] = {swa.x, swa.y, swa.z, swa.w, swb.x, swb.y, swb.z, swb.w};
    float4 a14 = *(const float4*)&stats[768 + 64 * p + o0];
    float4 c14 = *(const float4*)&stats[896 + 64 * p + o0];
    float a1v[4] = {a14.x, a14.y, a14.z, a14.w};
    float c1v[4] = {c14.x, c14.y, c14.z, c14.w};
    float r4[4];
#pragma unroll
    for (int i = 0; i < 4; ++i) {
      float r = 0.f;
#pragma unroll
      for (int j = 0; j < 8; ++j) {
        float msg = fmaxf(fmaf(a1v[i], acc2[i * 8 + j], c1v[i]), 0.f);
        r = fmaf(msg, wv[j], r);
      }
      r4[i] = r;
    }
#pragma unroll
    for (int i = 0; i < 4; ++i) {  // sum the 4 neighbor-subgroups (lane strides 16,32)
      float r = r4[i];
      r += __shfl_xor(r, 16, 64);
      r += __shfl_xor(r, 32, 64);
      r4[i] = r;
    }
    if ((t & 63) < 16) {
      float4 ysv = *(const float4*)&ys[((size_t)(b * Mn + m0 + m)) * 128 + 64 * p + o0];
      float4 as4 = *(const float4*)&stats[1024 + 64 * p + o0];
      float4 cs4 = *(const float4*)&stats[1152 + 64 * p + o0];
      float yv[4] = {ysv.x, ysv.y, ysv.z, ysv.w};
      float av[4] = {as4.x, as4.y, as4.z, as4.w};
      float cv[4] = {cs4.x, cs4.y, cs4.z, cs4.w};
#pragma unroll
      for (int i = 0; i < 4; ++i)
        red[(64 * p + o0 + i) * 5 + m] = fmaxf(r4[i] + fmaf(av[i], yv[i], cv[i]), 0.f);
    }
  }
  __syncthreads();
  for (int e = t; e < 512; e += 256) {
    int oo = e >> 2, mm = e & 3;
    out_feat[(size_t)b * 131072 + (size_t)oo * 1024 + m0 + mm] = red[oo * 5 + mm];
  }
}

// ---------------------------------------------------------------------------
extern "C" void kernel_launch(void* const* d_in, const int* in_sizes, int n_in,
                              void* d_out, int out_size, void* d_ws, size_t ws_size,
                              hipStream_t stream) {
  const float* coords = (const float*)d_in[0];
  const float* feats  = (const float*)d_in[1];
  const float* W0 = (const float*)d_in[2];
  const float* g0 = (const float*)d_in[3];
  const float* b0 = (const float*)d_in[4];
  const float* W1 = (const float*)d_in[5];
  const float* g1 = (const float*)d_in[6];
  const float* b1 = (const float*)d_in[7];
  const float* Ws = (const float*)d_in[8];
  const float* gs = (const float*)d_in[9];
  const float* bs = (const float*)d_in[10];

  float* out_coords = (float*)d_out;
  float* out_feat   = out_coords + (size_t)Bn * Mn * 3;

  char* w = (char*)d_ws;
  float*    featsT = (float*)w;    w += (size_t)Bn * Nn * CIN * 4;   // 8 MB
  uint32_t* sidx   = (uint32_t*)w; w += (size_t)Bn * Mn * 4;
  uint32_t* gidx   = (uint32_t*)w; w += (size_t)Bn * Mn * Kn * 4;
  float*    wts    = (float*)w;    w += (size_t)Bn * Mn * Kn * 4;
  float*    ys     = (float*)w;    w += (size_t)Bn * Mn * COUT * 4;  // 4 MB
  float*    stats  = (float*)w;    w += 1280 * 4;

  hipMemsetAsync(stats, 0, 640 * 4, stream);
  hipLaunchKernelGGL(k_tr,    dim3(512),  dim3(256), 0, stream, feats, featsT);
  hipLaunchKernelGGL(k_fps,   dim3(8),    dim3(512), 0, stream, coords, sidx, out_coords);
  hipLaunchKernelGGL(k_knn,   dim3(8192), dim3(256), 0, stream, coords, sidx, gidx, wts);
  hipLaunchKernelGGL(k_conv1, dim3(2048), dim3(256), 0, stream, coords, featsT, sidx, gidx, W0, stats);
  hipLaunchKernelGGL(k_skip,  dim3(128),  dim3(256), 0, stream, featsT, sidx, Ws, ys, stats);
  hipLaunchKernelGGL(k_fin0,  dim3(1),    dim3(64),  0, stream, stats, g0, b0);
  hipLaunchKernelGGL(k_conv2, dim3(2048), dim3(256), 0, stream, coords, featsT, sidx, gidx, W0, W1, stats);
  hipLaunchKernelGGL(k_fin1,  dim3(1),    dim3(128), 0, stream, stats, g1, b1, gs, bs);
  hipLaunchKernelGGL(k_out,   dim3(2048), dim3(256), 0, stream, coords, featsT, sidx, gidx, W0, W1, wts, ys, stats, out_feat);
}

// Round 8
// 1100.399 us; speedup vs baseline: 1.9369x; 1.9369x over previous
//
#include <hip/hip_runtime.h>
#include <hip/hip_bf16.h>
#include <cstdint>

#define DEV __device__ __forceinline__

// Problem constants (from setup_inputs)
constexpr int Bn   = 8;
constexpr int Nn   = 4096;
constexpr int Mn   = 1024;   // N / STRIDE
constexpr int Kn   = 32;     // NSAMPLE
constexpr int CIN  = 64;
constexpr int COUT = 128;

// ---------------------------------------------------------------------------
// FPS v4 helpers (R6 config: best measured 696 us) — byte-identical logic.
// ---------------------------------------------------------------------------
DEV float wave_max_f32(float x) {
#if __has_builtin(__builtin_amdgcn_update_dpp)
#define FSTEP(CTRL, RMASK)                                                      \
  {                                                                             \
    int o = __builtin_amdgcn_update_dpp(0, __float_as_int(x), CTRL, RMASK, 0xf, \
                                        false);                                 \
    x = fmaxf(x, __int_as_float(o));                                            \
  }
  FSTEP(0x111, 0xf)  // row_shr:1
  FSTEP(0x112, 0xf)  // row_shr:2
  FSTEP(0x114, 0xf)  // row_shr:4
  FSTEP(0x118, 0xf)  // row_shr:8
  FSTEP(0x142, 0xa)  // row_bcast:15 rows 1,3
  FSTEP(0x143, 0xc)  // row_bcast:31 rows 2,3
#undef FSTEP
#else
  for (int off = 1; off < 64; off <<= 1) x = fmaxf(x, __shfl_xor(x, off, 64));
#endif
  return x;  // lane 63 holds the wave max
}

DEV unsigned long long grp8_max_u64(unsigned long long k) {
#if __has_builtin(__builtin_amdgcn_update_dpp)
#define USTEP(CTRL)                                                                    \
  {                                                                                    \
    unsigned int lo = (unsigned int)__builtin_amdgcn_update_dpp(                       \
        0, (int)(unsigned int)k, CTRL, 0xf, 0xf, false);                               \
    unsigned int hi = (unsigned int)__builtin_amdgcn_update_dpp(                       \
        0, (int)(unsigned int)(k >> 32), CTRL, 0xf, 0xf, false);                       \
    unsigned long long o = ((unsigned long long)hi << 32) | lo;                        \
    if (o > k) k = o;                                                                  \
  }
  USTEP(0x111)  // row_shr:1
  USTEP(0x112)  // row_shr:2
  USTEP(0x114)  // row_shr:4
#undef USTEP
#else
  for (int off = 1; off < 8; off <<= 1) {
    unsigned int lo = __shfl_xor((unsigned int)k, off, 64);
    unsigned int hi = __shfl_xor((unsigned int)(k >> 32), off, 64);
    unsigned long long o = ((unsigned long long)hi << 32) | lo;
    if (o > k) k = o;
  }
#endif
  return k;  // lane 7 of each row holds max of that row's lanes 0..7
}

DEV uint32_t fps_round8(const float v[8], int t, unsigned long long (*part)[8], int p) {
  float v4[4]; int j4[4];
#pragma unroll
  for (int i = 0; i < 4; ++i) {
    bool r = v[2 * i + 1] > v[2 * i];
    v4[i] = r ? v[2 * i + 1] : v[2 * i];
    j4[i] = r ? 2 * i + 1 : 2 * i;
  }
  float v2[2]; int j2[2];
#pragma unroll
  for (int i = 0; i < 2; ++i) {
    bool r = v4[2 * i + 1] > v4[2 * i];
    v2[i] = r ? v4[2 * i + 1] : v4[2 * i];
    j2[i] = r ? j4[2 * i + 1] : j4[2 * i];
  }
  bool rr = v2[1] > v2[0];
  float bv = rr ? v2[1] : v2[0];
  int bj = rr ? j2[1] : j2[0];

  float wl = wave_max_f32(bv);
  float wmax = __int_as_float(__builtin_amdgcn_readlane(__float_as_int(wl), 63));
  unsigned long long mask = __ballot(bv == wmax);
  int Ls = (int)__ffsll(mask) - 1;           // lowest lane with the max
  int bjw = __shfl(bj, Ls, 64);              // its local index (Ls uniform)
  uint32_t idx = 8u * (uint32_t)((t & ~63) + Ls) + (uint32_t)bjw;
  const int sl = p & 1;
  if ((t & 63) == 0)
    part[sl][t >> 6] = ((unsigned long long)__float_as_uint(wmax) << 12) |
                       (unsigned long long)(4095u - idx);
  __syncthreads();
  unsigned long long kk = part[sl][t & 7];
  kk = grp8_max_u64(kk);
  unsigned int lo = (unsigned int)__builtin_amdgcn_readlane((int)(unsigned int)kk, 7);
  return 4095u - (lo & 4095u);
}

// ---------------------------------------------------------------------------
// Fused kernel: blocks 0..7 = FPS (R6 v4, 512 thr, 8 contiguous pts/thread);
// blocks 8..519 = feats transpose (runs on idle CUs during FPS).
// ---------------------------------------------------------------------------
__global__ __launch_bounds__(512, 1) void k_fused(const float* __restrict__ coords,
                                                  const float* __restrict__ feats,
                                                  float* __restrict__ featsT,
                                                  uint32_t* __restrict__ sidx,
                                                  float* __restrict__ outc) {
  __shared__ __align__(16) char smraw[Nn * 16];   // sp[Nn] | tile[64][65]
  __shared__ unsigned long long part[2][8];
  __shared__ uint32_t farl[Mn];
  __shared__ float s_mean[4];
  const int t = threadIdx.x;

  if (blockIdx.x >= 8) {  // ---- transpose role ----
    float (*tile)[65] = (float(*)[65])smraw;
    int bid = blockIdx.x - 8;
    int b = bid >> 6, n0 = (bid & 63) * 64;
    int lane = t & 63, grp = t >> 6;  // 8 groups of 64
    for (int r = 0; r < 8; ++r) {
      int c = grp + r * 8;
      tile[c][lane] = feats[((size_t)b * 64 + c) * 4096 + n0 + lane];
    }
    __syncthreads();
    for (int r = 0; r < 8; ++r) {
      int n = grp + r * 8;
      featsT[((size_t)b * 4096 + n0 + n) * 64 + lane] = tile[lane][n];
    }
    return;
  }

  // ---- FPS role (R6 body) ----
  float4* sp = (float4*)smraw;
  const int b = blockIdx.x;
  const float* cb = coords + (size_t)b * Nn * 3;
  for (int i = t; i < Nn; i += 512)
    sp[i] = make_float4(cb[3 * i], cb[3 * i + 1], cb[3 * i + 2], 0.f);
  __syncthreads();
  if (t == 0) {  // sequential in-order fp32 mean (numpy reduce order; proven)
    float ax = 0.f, ay = 0.f, az = 0.f;
    for (int i = 0; i < Nn; ++i) {
      float4 c = sp[i];
      ax = __fadd_rn(ax, c.x); ay = __fadd_rn(ay, c.y); az = __fadd_rn(az, c.z);
    }
    s_mean[0] = __fdiv_rn(ax, 4096.f);
    s_mean[1] = __fdiv_rn(ay, 4096.f);
    s_mean[2] = __fdiv_rn(az, 4096.f);
  }
  __syncthreads();

  float px[8], py[8], pz[8], md[8];
#pragma unroll
  for (int j = 0; j < 8; ++j) {
    float4 c = sp[8 * t + j];                   // contiguous per thread
    px[j] = c.x; py[j] = c.y; pz[j] = c.z;
    md[j] = __builtin_inff();
  }

  uint32_t far;
  {
    float mx = s_mean[0], my = s_mean[1], mz = s_mean[2];
    float tv[8];
#pragma unroll
    for (int j = 0; j < 8; ++j) {
      float dx = __fsub_rn(px[j], mx), dy = __fsub_rn(py[j], my), dz = __fsub_rn(pz[j], mz);
      tv[j] = __fadd_rn(__fadd_rn(__fmul_rn(dx, dx), __fmul_rn(dy, dy)), __fmul_rn(dz, dz));
    }
    far = fps_round8(tv, t, part, 0);
  }

  for (int p = 1; p < Mn; ++p) {
    if (t == 0) farl[p - 1] = far;
    float4 c = sp[far];
#pragma unroll
    for (int j = 0; j < 8; ++j) {
      float dx = __fsub_rn(px[j], c.x), dy = __fsub_rn(py[j], c.y), dz = __fsub_rn(pz[j], c.z);
      float d = __fadd_rn(__fadd_rn(__fmul_rn(dx, dx), __fmul_rn(dy, dy)), __fmul_rn(dz, dz));
      md[j] = fminf(md[j], d);
    }
    far = fps_round8(md, t, part, p);
  }
  if (t == 0) farl[Mn - 1] = far;
  __syncthreads();

  for (int i = t; i < Mn; i += 512) {
    uint32_t f = farl[i];
    sidx[b * Mn + i] = f;
    float4 c = sp[f];
    outc[(size_t)(b * Mn + i) * 3 + 0] = c.x;
    outc[(size_t)(b * Mn + i) * 3 + 1] = c.y;
    outc[(size_t)(b * Mn + i) * 3 + 2] = c.z;
  }
}

// ---------------------------------------------------------------------------
// 32-NN per query (== reference ball_query+knn fallback) + density weights.
// ---------------------------------------------------------------------------
__global__ __launch_bounds__(256) void k_knn(const float* __restrict__ coords,
                                             const uint32_t* __restrict__ sidx,
                                             uint32_t* __restrict__ gidx,
                                             float* __restrict__ wts) {
  const int q = blockIdx.x;
  const int b = q >> 10;
  const int t = threadIdx.x;
  __shared__ unsigned long long keys[Nn + 2];
  __shared__ int s_cnt;
  __shared__ float s_q[4];
  __shared__ uint32_t s_sel[32];
  __shared__ float gx[32], gy[32], gz[32], g2[32];
  __shared__ float dmat[32 * 33];
  __shared__ float kth[32];
  __shared__ float s_raw[32];
  __shared__ float s_sum;

  if (t == 0) {
    uint32_t si = sidx[q];
    const float* c = &coords[((size_t)b * Nn + si) * 3];
    s_q[0] = c[0]; s_q[1] = c[1]; s_q[2] = c[2];
  }
  __syncthreads();
  float qx = s_q[0], qy = s_q[1], qz = s_q[2];
  float q2 = __fadd_rn(__fadd_rn(__fmul_rn(qx, qx), __fmul_rn(qy, qy)), __fmul_rn(qz, qz));
  const float* cb = coords + (size_t)b * Nn * 3;

  float thr = 0.04f;
  int cnt = 0;
  while (true) {
    if (t == 0) s_cnt = 0;
    __syncthreads();
    for (int j = 0; j < 16; ++j) {
      int i = t + 256 * j;
      float cx = cb[3 * i], cy = cb[3 * i + 1], cz = cb[3 * i + 2];
      float c2  = __fadd_rn(__fadd_rn(__fmul_rn(cx, cx), __fmul_rn(cy, cy)), __fmul_rn(cz, cz));
      float dot = __fadd_rn(__fadd_rn(__fmul_rn(qx, cx), __fmul_rn(qy, cy)), __fmul_rn(qz, cz));
      float d2  = __fsub_rn(__fadd_rn(q2, c2), __fmul_rn(2.f, dot));
      float d2c = fmaxf(d2, 1e-12f);
      bool pred = (d2c <= thr);
      unsigned long long mk = __ballot(pred);
      int base = 0;
      if ((t & 63) == 0 && mk) base = atomicAdd(&s_cnt, (int)__popcll(mk));
      base = __shfl(base, 0, 64);
      if (pred) {
        int pos = base + (int)__popcll(mk & ((1ull << (t & 63)) - 1ull));
        keys[pos] = ((unsigned long long)__float_as_uint(d2c) << 32) | (uint32_t)i;
      }
    }
    __syncthreads();
    cnt = s_cnt;
    if (cnt >= 32 || thr > 1.f) break;
    thr = (thr < 0.1f) ? 0.16f : 8.f;
    __syncthreads();
  }
  if (t == 0) { keys[cnt] = ~0ull; keys[cnt + 1] = ~0ull; }
  __syncthreads();
  int cnt2 = (cnt + 1) & ~1;
  for (int i = t; i < cnt; i += 256) {
    unsigned long long ki = keys[i];
    int r = 0;
    for (int j2 = 0; j2 < cnt2; j2 += 2) {
      unsigned long long a = keys[j2], c2 = keys[j2 + 1];
      r += (a < ki) + (c2 < ki);
    }
    if (r < 32) s_sel[r] = (uint32_t)ki;
  }
  __syncthreads();

  if (t < 32) {
    uint32_t gi = s_sel[t];
    gidx[(size_t)q * 32 + t] = gi;
    const float* c = &coords[((size_t)b * Nn + gi) * 3];
    float x = c[0], y = c[1], z = c[2];
    gx[t] = x; gy[t] = y; gz[t] = z;
    g2[t] = __fadd_rn(__fadd_rn(__fmul_rn(x, x), __fmul_rn(y, y)), __fmul_rn(z, z));
  }
  __syncthreads();
  for (int p = t; p < 1024; p += 256) {
    int i = p >> 5, jj = p & 31;
    float dot = __fadd_rn(__fadd_rn(__fmul_rn(gx[i], gx[jj]), __fmul_rn(gy[i], gy[jj])),
                          __fmul_rn(gz[i], gz[jj]));
    float d2 = __fsub_rn(__fadd_rn(g2[i], g2[jj]), __fmul_rn(2.f, dot));
    float dd = sqrtf(fmaxf(d2, 1e-12f));
    if (i == jj) dd = __builtin_inff();
    dmat[i * 33 + jj] = dd;
  }
  __syncthreads();
  for (int p = t; p < 1024; p += 256) {
    int i = p >> 5, jj = p & 31;
    float v = dmat[i * 33 + jj];
    int r = 0;
    for (int c = 0; c < 32; ++c) {
      float u = dmat[i * 33 + c];
      r += (u < v) || (u == v && c < jj);
    }
    if (r == 15) kth[i] = v;
  }
  __syncthreads();
  if (t < 32) { float x = fmaxf(kth[t], 1e-8f); s_raw[t] = x * x * x; }
  __syncthreads();
  if (t == 0) {
    float s = 0.f;
    for (int i2 = 0; i2 < 32; ++i2) s += s_raw[i2];
    s_sum = fmaxf(s, 1e-8f);
  }
  __syncthreads();
  if (t < 32) wts[(size_t)q * 32 + t] = s_raw[t] / s_sum;
}

// ---------------------------------------------------------------------------
// Conv pipeline. Tile = 4 queries x 32 neighbors (GEMM k-dim = 128).
// ---------------------------------------------------------------------------
constexpr int XST = 132;
constexpr int WST = 68;

DEV void build_x(const float* __restrict__ coords, const float* __restrict__ featsT,
                 const uint32_t* __restrict__ sidx, const uint32_t* __restrict__ gidx,
                 const float* __restrict__ W0, int b, int m0, int t,
                 float* xs, float* w0sT, uint32_t* s_gi, float* s_qc) {
  for (int i = t; i < 64 * 67; i += 256) {
    int o = i / 67, c = i - o * 67;
    w0sT[c * WST + o] = W0[i];
  }
  if (t < 128) {
    s_gi[t] = gidx[((size_t)(b * Mn + m0)) * 32 + t];
  } else if (t < 132) {
    int mm = t - 128;
    uint32_t si = sidx[b * Mn + m0 + mm];
    const float* c = &coords[((size_t)b * Nn + si) * 3];
    s_qc[mm * 3 + 0] = c[0]; s_qc[mm * 3 + 1] = c[1]; s_qc[mm * 3 + 2] = c[2];
  }
  __syncthreads();
  if (t < 128) {
    int mm = t >> 5;
    const float* c = &coords[((size_t)b * Nn + s_gi[t]) * 3];
    xs[0 * XST + t] = (c[0] - s_qc[mm * 3 + 0]) / 0.2f;
    xs[1 * XST + t] = (c[1] - s_qc[mm * 3 + 1]) / 0.2f;
    xs[2 * XST + t] = (c[2] - s_qc[mm * 3 + 2]) / 0.2f;
  }
  {
    int c = t & 63, k0g = t >> 6;
    for (int r2 = 0; r2 < 32; ++r2) {
      int kk = k0g + 4 * r2;
      xs[(size_t)(3 + c) * XST + kk] = featsT[((size_t)b * Nn + s_gi[kk]) * 64 + c];
    }
  }
  __syncthreads();
}

DEV void conv1_acc(const float* xs, const float* w0sT, int o0, int k0, float acc[32]) {
#pragma unroll
  for (int i = 0; i < 32; ++i) acc[i] = 0.f;
  for (int c = 0; c < 67; ++c) {
    float4 w  = *(const float4*)&w0sT[c * WST + o0];
    float4 xa = *(const float4*)&xs[c * XST + k0];
    float4 xb = *(const float4*)&xs[c * XST + k0 + 4];
    float wv[4] = {w.x, w.y, w.z, w.w};
    float xv[8] = {xa.x, xa.y, xa.z, xa.w, xb.x, xb.y, xb.z, xb.w};
#pragma unroll
    for (int i = 0; i < 4; ++i)
#pragma unroll
      for (int j = 0; j < 8; ++j)
        acc[i * 8 + j] = fmaf(wv[i], xv[j], acc[i * 8 + j]);
  }
}

DEV void conv2_acc(const float* hs, const float* w1sT, int o0, int k0, float acc2[32]) {
#pragma unroll
  for (int i = 0; i < 32; ++i) acc2[i] = 0.f;
  for (int c = 0; c < 64; ++c) {
    float4 w  = *(const float4*)&w1sT[c * WST + o0];
    float4 xa = *(const float4*)&hs[c * XST + k0];
    float4 xb = *(const float4*)&hs[c * XST + k0 + 4];
    float wv[4] = {w.x, w.y, w.z, w.w};
    float xv[8] = {xa.x, xa.y, xa.z, xa.w, xb.x, xb.y, xb.z, xb.w};
#pragma unroll
    for (int i = 0; i < 4; ++i)
#pragma unroll
      for (int j = 0; j < 8; ++j)
        acc2[i * 8 + j] = fmaf(wv[i], xv[j], acc2[i * 8 + j]);
  }
}

// stats layout (floats): [0,64) s0 | [64,128) q0 | [128,256) s1 | [256,384) q1
// | [384,512) ss | [512,640) qs | 640 a0 | 704 c0 | 768 a1 | 896 c1
// | 1024 as | 1152 cs   (640+ used only by fallback path)
__global__ __launch_bounds__(256) void k_conv1(const float* __restrict__ coords,
                                               const float* __restrict__ featsT,
                                               const uint32_t* __restrict__ sidx,
                                               const uint32_t* __restrict__ gidx,
                                               const float* __restrict__ W0,
                                               float* __restrict__ stats,
                                               unsigned short* __restrict__ accb) {
  __shared__ float xs[67 * XST];
  __shared__ float w0sT[67 * WST];
  __shared__ uint32_t s_gi[128];
  __shared__ float s_qc[12];
  __shared__ float ssum[64], ssq[64];
  int blk = blockIdx.x, t = threadIdx.x;
  int b = blk >> 8, m0 = (blk & 255) << 2;
  if (t < 64) { ssum[t] = 0.f; ssq[t] = 0.f; }
  build_x(coords, featsT, sidx, gidx, W0, b, m0, t, xs, w0sT, s_gi, s_qc);
  int o0 = (t & 15) * 4, k0 = (t >> 4) * 8;
  float acc[32];
  conv1_acc(xs, w0sT, o0, k0, acc);
  if (accb != nullptr) {  // cache pre-BN conv1 output as bf16 (RNE)
    unsigned short* at = accb + (size_t)blk * 8192;
#pragma unroll
    for (int i = 0; i < 4; ++i) {
      unsigned int w[4];
#pragma unroll
      for (int q = 0; q < 4; ++q) {
        __hip_bfloat16 h0 = __float2bfloat16(acc[i * 8 + 2 * q]);
        __hip_bfloat16 h1 = __float2bfloat16(acc[i * 8 + 2 * q + 1]);
        unsigned short u0 = *reinterpret_cast<unsigned short*>(&h0);
        unsigned short u1 = *reinterpret_cast<unsigned short*>(&h1);
        w[q] = (unsigned int)u0 | ((unsigned int)u1 << 16);
      }
      uint4 v = make_uint4(w[0], w[1], w[2], w[3]);
      *(uint4*)&at[(o0 + i) * 128 + k0] = v;
    }
  }
#pragma unroll
  for (int i = 0; i < 4; ++i) {
    float s = 0.f, sq = 0.f;
#pragma unroll
    for (int j = 0; j < 8; ++j) { s += acc[i * 8 + j]; sq = fmaf(acc[i * 8 + j], acc[i * 8 + j], sq); }
    atomicAdd(&ssum[o0 + i], s); atomicAdd(&ssq[o0 + i], sq);
  }
  __syncthreads();
  if (t < 64) { atomicAdd(&stats[t], ssum[t]); atomicAdd(&stats[64 + t], ssq[t]); }
}

// ---- cached-path conv2: read bf16 acc, in-kernel fin0 ----
__global__ __launch_bounds__(256) void k_conv2c(const unsigned short* __restrict__ accb,
                                                const float* __restrict__ W1,
                                                float* __restrict__ stats,
                                                const float* __restrict__ g0,
                                                const float* __restrict__ b0) {
  __shared__ float hs[64 * XST];
  __shared__ float w1sT[64 * WST];
  __shared__ float s_a0[64], s_c0[64];
  __shared__ float ssum[128], ssq[128];
  int blk = blockIdx.x, t = threadIdx.x;
  if (t < 128) { ssum[t] = 0.f; ssq[t] = 0.f; }
  if (t < 64) {
    float mu  = stats[t] * (1.f / 262144.f);
    float var = stats[64 + t] * (1.f / 262144.f) - mu * mu;
    float a = g0[t] / sqrtf(var + 1e-5f);
    s_a0[t] = a; s_c0[t] = b0[t] - mu * a;
  }
  const unsigned short* at = accb + (size_t)blk * 8192;
  int o = t >> 2, kb = (t & 3) * 32;
  __syncthreads();
  float a0 = s_a0[o], c0 = s_c0[o];
#pragma unroll
  for (int g = 0; g < 4; ++g) {
    uint4 v = *(const uint4*)&at[o * 128 + kb + 8 * g];
    unsigned int vv[4] = {v.x, v.y, v.z, v.w};
#pragma unroll
    for (int q = 0; q < 4; ++q) {
      float f0 = __uint_as_float((vv[q] & 0xffffu) << 16);
      float f1 = __uint_as_float(vv[q] & 0xffff0000u);
      hs[o * XST + kb + 8 * g + 2 * q]     = fmaxf(fmaf(a0, f0, c0), 0.f);
      hs[o * XST + kb + 8 * g + 2 * q + 1] = fmaxf(fmaf(a0, f1, c0), 0.f);
    }
  }
  int o0 = (t & 15) * 4, k0 = (t >> 4) * 8;
  for (int p = 0; p < 2; ++p) {
    __syncthreads();
    for (int i = t; i < 64 * 64; i += 256) {
      int oo = i >> 6, cc = i & 63;
      w1sT[cc * WST + oo] = W1[(size_t)(64 * p + oo) * 64 + cc];
    }
    __syncthreads();
    float acc2[32];
    conv2_acc(hs, w1sT, o0, k0, acc2);
#pragma unroll
    for (int i = 0; i < 4; ++i) {
      float s = 0.f, sq = 0.f;
#pragma unroll
      for (int j = 0; j < 8; ++j) { s += acc2[i * 8 + j]; sq = fmaf(acc2[i * 8 + j], acc2[i * 8 + j], sq); }
      atomicAdd(&ssum[64 * p + o0 + i], s); atomicAdd(&ssq[64 * p + o0 + i], sq);
    }
  }
  __syncthreads();
  if (t < 128) { atomicAdd(&stats[128 + t], ssum[t]); atomicAdd(&stats[256 + t], ssq[t]); }
}

// ---- cached-path output kernel: in-kernel fin0+fin1 ----
__global__ __launch_bounds__(256) void k_outc(const unsigned short* __restrict__ accb,
                                              const float* __restrict__ W1,
                                              const float* __restrict__ wts,
                                              const float* __restrict__ ys,
                                              const float* __restrict__ stats,
                                              const float* __restrict__ g0,
                                              const float* __restrict__ b0,
                                              const float* __restrict__ g1,
                                              const float* __restrict__ b1,
                                              const float* __restrict__ gs,
                                              const float* __restrict__ bs,
                                              float* __restrict__ out_feat) {
  __shared__ float hs[64 * XST];
  __shared__ float w1sT[64 * WST];
  __shared__ float s_a0[64], s_c0[64];
  __shared__ float s_a1[128], s_c1[128], s_as[128], s_cs[128];
  __shared__ __align__(16) float sw[4 * 36];
  __shared__ float red[128 * 5];
  int blk = blockIdx.x, t = threadIdx.x;
  int b = blk >> 8, m0 = (blk & 255) << 2;
  if (t < 64) {
    float mu  = stats[t] * (1.f / 262144.f);
    float var = stats[64 + t] * (1.f / 262144.f) - mu * mu;
    float a = g0[t] / sqrtf(var + 1e-5f);
    s_a0[t] = a; s_c0[t] = b0[t] - mu * a;
  }
  if (t < 128) {
    float mu  = stats[128 + t] * (1.f / 262144.f);
    float var = stats[256 + t] * (1.f / 262144.f) - mu * mu;
    float a = g1[t] / sqrtf(var + 1e-5f);
    s_a1[t] = a; s_c1[t] = b1[t] - mu * a;
    float mus  = stats[384 + t] * (1.f / 8192.f);
    float vars = stats[512 + t] * (1.f / 8192.f) - mus * mus;
    float as = gs[t] / sqrtf(vars + 1e-5f);
    s_as[t] = as; s_cs[t] = bs[t] - mus * as;
    sw[(t >> 5) * 36 + (t & 31)] = wts[((size_t)(b * Mn + m0)) * 32 + t];
  }
  const unsigned short* at = accb + (size_t)blk * 8192;
  int o = t >> 2, kb = (t & 3) * 32;
  __syncthreads();
  float a0 = s_a0[o], c0 = s_c0[o];
#pragma unroll
  for (int g = 0; g < 4; ++g) {
    uint4 v = *(const uint4*)&at[o * 128 + kb + 8 * g];
    unsigned int vv[4] = {v.x, v.y, v.z, v.w};
#pragma unroll
    for (int q = 0; q < 4; ++q) {
      float f0 = __uint_as_float((vv[q] & 0xffffu) << 16);
      float f1 = __uint_as_float(vv[q] & 0xffff0000u);
      hs[o * XST + kb + 8 * g + 2 * q]     = fmaxf(fmaf(a0, f0, c0), 0.f);
      hs[o * XST + kb + 8 * g + 2 * q + 1] = fmaxf(fmaf(a0, f1, c0), 0.f);
    }
  }
  int o0 = (t & 15) * 4, k0 = (t >> 4) * 8;
  int m = k0 >> 5, nb0 = k0 & 31;
  for (int p = 0; p < 2; ++p) {
    __syncthreads();
    for (int i = t; i < 64 * 64; i += 256) {
      int oo = i >> 6, cc = i & 63;
      w1sT[cc * WST + oo] = W1[(size_t)(64 * p + oo) * 64 + cc];
    }
    __syncthreads();
    float acc2[32];
    conv2_acc(hs, w1sT, o0, k0, acc2);
    float4 swa = *(const float4*)&sw[m * 36 + nb0];
    float4 swb = *(const float4*)&sw[m * 36 + nb0 + 4];
    float wv[8] = {swa.x, swa.y, swa.z, swa.w, swb.x, swb.y, swb.z, swb.w};
    float a1v[4], c1v[4];
#pragma unroll
    for (int i = 0; i < 4; ++i) { a1v[i] = s_a1[64 * p + o0 + i]; c1v[i] = s_c1[64 * p + o0 + i]; }
    float r4[4];
#pragma unroll
    for (int i = 0; i < 4; ++i) {
      float r = 0.f;
#pragma unroll
      for (int j = 0; j < 8; ++j) {
        float msg = fmaxf(fmaf(a1v[i], acc2[i * 8 + j], c1v[i]), 0.f);
        r = fmaf(msg, wv[j], r);
      }
      r4[i] = r;
    }
#pragma unroll
    for (int i = 0; i < 4; ++i) {
      float r = r4[i];
      r += __shfl_xor(r, 16, 64);
      r += __shfl_xor(r, 32, 64);
      r4[i] = r;
    }
    if ((t & 63) < 16) {
      float4 ysv = *(const float4*)&ys[((size_t)(b * Mn + m0 + m)) * 128 + 64 * p + o0];
      float yv[4] = {ysv.x, ysv.y, ysv.z, ysv.w};
#pragma unroll
      for (int i = 0; i < 4; ++i) {
        int o2 = 64 * p + o0 + i;
        red[o2 * 5 + m] = fmaxf(r4[i] + fmaf(s_as[o2], yv[i], s_cs[o2]), 0.f);
      }
    }
  }
  __syncthreads();
  for (int e = t; e < 512; e += 256) {
    int oo = e >> 2, mm = e & 3;
    out_feat[(size_t)b * 131072 + (size_t)oo * 1024 + m0 + mm] = red[oo * 5 + mm];
  }
}

// ---------------------------------------------------------------------------
// Fallback path (ws too small): R6 kernels
// ---------------------------------------------------------------------------
__global__ void k_fin0(float* stats, const float* g0, const float* b0) {
  int t = threadIdx.x;
  if (t >= 64) return;
  float mu  = stats[t] * (1.f / 262144.f);
  float var = stats[64 + t] * (1.f / 262144.f) - mu * mu;
  float a = g0[t] / sqrtf(var + 1e-5f);
  stats[640 + t] = a;
  stats[704 + t] = b0[t] - mu * a;
}

__global__ __launch_bounds__(256) void k_conv2(const float* __restrict__ coords,
                                               const float* __restrict__ featsT,
                                               const uint32_t* __restrict__ sidx,
                                               const uint32_t* __restrict__ gidx,
                                               const float* __restrict__ W0,
                                               const float* __restrict__ W1,
                                               float* __restrict__ stats) {
  __shared__ float smU[13400];
  __shared__ uint32_t s_gi[128];
  __shared__ float s_qc[12];
  __shared__ float ssum[128], ssq[128];
  float* xs = smU;  float* w0sT = smU + 67 * XST;
  float* hs = smU;  float* w1sT = smU + 64 * XST;
  int blk = blockIdx.x, t = threadIdx.x;
  int b = blk >> 8, m0 = (blk & 255) << 2;
  if (t < 128) { ssum[t] = 0.f; ssq[t] = 0.f; }
  build_x(coords, featsT, sidx, gidx, W0, b, m0, t, xs, w0sT, s_gi, s_qc);
  int o0 = (t & 15) * 4, k0 = (t >> 4) * 8;
  float acc[32];
  conv1_acc(xs, w0sT, o0, k0, acc);
  float4 a04 = *(const float4*)&stats[640 + o0];
  float4 c04 = *(const float4*)&stats[704 + o0];
  float a0v[4] = {a04.x, a04.y, a04.z, a04.w};
  float c0v[4] = {c04.x, c04.y, c04.z, c04.w};
  __syncthreads();
#pragma unroll
  for (int i = 0; i < 4; ++i) {
    float h[8];
#pragma unroll
    for (int j = 0; j < 8; ++j) h[j] = fmaxf(fmaf(a0v[i], acc[i * 8 + j], c0v[i]), 0.f);
    *(float4*)&hs[(o0 + i) * XST + k0]     = make_float4(h[0], h[1], h[2], h[3]);
    *(float4*)&hs[(o0 + i) * XST + k0 + 4] = make_float4(h[4], h[5], h[6], h[7]);
  }
  for (int p = 0; p < 2; ++p) {
    __syncthreads();
    for (int i = t; i < 64 * 64; i += 256) {
      int oo = i >> 6, cc = i & 63;
      w1sT[cc * WST + oo] = W1[(size_t)(64 * p + oo) * 64 + cc];
    }
    __syncthreads();
    float acc2[32];
    conv2_acc(hs, w1sT, o0, k0, acc2);
#pragma unroll
    for (int i = 0; i < 4; ++i) {
      float s = 0.f, sq = 0.f;
#pragma unroll
      for (int j = 0; j < 8; ++j) { s += acc2[i * 8 + j]; sq = fmaf(acc2[i * 8 + j], acc2[i * 8 + j], sq); }
      atomicAdd(&ssum[64 * p + o0 + i], s); atomicAdd(&ssq[64 * p + o0 + i], sq);
    }
  }
  __syncthreads();
  if (t < 128) { atomicAdd(&stats[128 + t], ssum[t]); atomicAdd(&stats[256 + t], ssq[t]); }
}

__global__ __launch_bounds__(256) void k_skip(const float* __restrict__ featsT,
                                              const uint32_t* __restrict__ sidx,
                                              const float* __restrict__ Ws,
                                              float* __restrict__ ys,
                                              float* __restrict__ stats) {
  __shared__ float fin[64 * 65];
  __shared__ float wssT[64 * 129];
  __shared__ uint32_t s_si[64];
  __shared__ float ssum[128], ssq[128];
  int blk = blockIdx.x, t = threadIdx.x;
  int b = blk >> 4, m0 = (blk & 15) * 64;
  if (t < 64) s_si[t] = sidx[b * Mn + m0 + t];
  if (t < 128) { ssum[t] = 0.f; ssq[t] = 0.f; }
  __syncthreads();
  for (int i = t; i < 64 * 64; i += 256) {
    int mm = i >> 6, c = i & 63;
    fin[mm * 65 + c] = featsT[((size_t)b * Nn + s_si[mm]) * 64 + c];
  }
  for (int i = t; i < 128 * 64; i += 256) {
    int oo = i >> 6, cc = i & 63;
    wssT[cc * 129 + oo] = Ws[(size_t)oo * 64 + cc];
  }
  __syncthreads();
  int o = t & 127, mh = t >> 7;
  float s = 0.f, sq = 0.f;
  for (int mm = mh * 32; mm < mh * 32 + 32; ++mm) {
    float acc = 0.f;
    for (int c = 0; c < 64; ++c) acc = fmaf(wssT[c * 129 + o], fin[mm * 65 + c], acc);
    ys[((size_t)(b * Mn + m0 + mm)) * 128 + o] = acc;
    s += acc; sq = fmaf(acc, acc, sq);
  }
  atomicAdd(&ssum[o], s); atomicAdd(&ssq[o], sq);
  __syncthreads();
  if (t < 128) { atomicAdd(&stats[384 + t], ssum[t]); atomicAdd(&stats[512 + t], ssq[t]); }
}

__global__ void k_fin1(float* stats, const float* g1, const float* b1,
                       const float* gs, const float* bs) {
  int t = threadIdx.x;
  if (t >= 128) return;
  float mu  = stats[128 + t] * (1.f / 262144.f);
  float var = stats[256 + t] * (1.f / 262144.f) - mu * mu;
  float a = g1[t] / sqrtf(var + 1e-5f);
  stats[768 + t] = a;
  stats[896 + t] = b1[t] - mu * a;
  float mus  = stats[384 + t] * (1.f / 8192.f);
  float vars = stats[512 + t] * (1.f / 8192.f) - mus * mus;
  float as = gs[t] / sqrtf(vars + 1e-5f);
  stats[1024 + t] = as;
  stats[1152 + t] = bs[t] - mus * as;
}

__global__ __launch_bounds__(256) void k_out(const float* __restrict__ coords,
                                             const float* __restrict__ featsT,
                                             const uint32_t* __restrict__ sidx,
                                             const uint32_t* __restrict__ gidx,
                                             const float* __restrict__ W0,
                                             const float* __restrict__ W1,
                                             const float* __restrict__ wts,
                                             const float* __restrict__ ys,
                                             const float* __restrict__ stats,
                                             float* __restrict__ out_feat) {
  __shared__ float smU[13400];
  __shared__ uint32_t s_gi[128];
  __shared__ float s_qc[12];
  __shared__ __align__(16) float sw[4 * 36];
  __shared__ float red[128 * 5];
  float* xs = smU;  float* w0sT = smU + 67 * XST;
  float* hs = smU;  float* w1sT = smU + 64 * XST;
  int blk = blockIdx.x, t = threadIdx.x;
  int b = blk >> 8, m0 = (blk & 255) << 2;
  build_x(coords, featsT, sidx, gidx, W0, b, m0, t, xs, w0sT, s_gi, s_qc);
  if (t < 128) sw[(t >> 5) * 36 + (t & 31)] = wts[((size_t)(b * Mn + m0)) * 32 + t];
  int o0 = (t & 15) * 4, k0 = (t >> 4) * 8;
  int m = k0 >> 5, nb0 = k0 & 31;
  float acc[32];
  conv1_acc(xs, w0sT, o0, k0, acc);
  float4 a04 = *(const float4*)&stats[640 + o0];
  float4 c04 = *(const float4*)&stats[704 + o0];
  float a0v[4] = {a04.x, a04.y, a04.z, a04.w};
  float c0v[4] = {c04.x, c04.y, c04.z, c04.w};
  __syncthreads();
#pragma unroll
  for (int i = 0; i < 4; ++i) {
    float h[8];
#pragma unroll
    for (int j = 0; j < 8; ++j) h[j] = fmaxf(fmaf(a0v[i], acc[i * 8 + j], c0v[i]), 0.f);
    *(float4*)&hs[(o0 + i) * XST + k0]     = make_float4(h[0], h[1], h[2], h[3]);
    *(float4*)&hs[(o0 + i) * XST + k0 + 4] = make_float4(h[4], h[5], h[6], h[7]);
  }
  for (int p = 0; p < 2; ++p) {
    __syncthreads();
    for (int i = t; i < 64 * 64; i += 256) {
      int oo = i >> 6, cc = i & 63;
      w1sT[cc * WST + oo] = W1[(size_t)(64 * p + oo) * 64 + cc];
    }
    __syncthreads();
    float acc2[32];
    conv2_acc(hs, w1sT, o0, k0, acc2);
    float4 swa = *(const float4*)&sw[m * 36 + nb0];
    float4 swb = *(const float4*)&sw[m * 36 + nb0 + 4];
    float wv[8] = {swa.x, swa.y, swa.z, swa.w, swb.x, swb.y, swb.z, swb.w};
    float4 a14 = *(const float4*)&stats[768 + 64 * p + o0];
    float4 c14 = *(const float4*)&stats[896 + 64 * p + o0];
    float a1v[4] = {a14.x, a14.y, a14.z, a14.w};
    float c1v[4] = {c14.x, c14.y, c14.z, c14.w};
    float r4[4];
#pragma unroll
    for (int i = 0; i < 4; ++i) {
      float r = 0.f;
#pragma unroll
      for (int j = 0; j < 8; ++j) {
        float msg = fmaxf(fmaf(a1v[i], acc2[i * 8 + j], c1v[i]), 0.f);
        r = fmaf(msg, wv[j], r);
      }
      r4[i] = r;
    }
#pragma unroll
    for (int i = 0; i < 4; ++i) {
      float r = r4[i];
      r += __shfl_xor(r, 16, 64);
      r += __shfl_xor(r, 32, 64);
      r4[i] = r;
    }
    if ((t & 63) < 16) {
      float4 ysv = *(const float4*)&ys[((size_t)(b * Mn + m0 + m)) * 128 + 64 * p + o0];
      float4 as4 = *(const float4*)&stats[1024 + 64 * p + o0];
      float4 cs4 = *(const float4*)&stats[1152 + 64 * p + o0];
      float yv[4] = {ysv.x, ysv.y, ysv.z, ysv.w};
      float av[4] = {as4.x, as4.y, as4.z, as4.w};
      float cv[4] = {cs4.x, cs4.y, cs4.z, cs4.w};
#pragma unroll
      for (int i = 0; i < 4; ++i)
        red[(64 * p + o0 + i) * 5 + m] = fmaxf(r4[i] + fmaf(av[i], yv[i], cv[i]), 0.f);
    }
  }
  __syncthreads();
  for (int e = t; e < 512; e += 256) {
    int oo = e >> 2, mm = e & 3;
    out_feat[(size_t)b * 131072 + (size_t)oo * 1024 + m0 + mm] = red[oo * 5 + mm];
  }
}

// ---------------------------------------------------------------------------
extern "C" void kernel_launch(void* const* d_in, const int* in_sizes, int n_in,
                              void* d_out, int out_size, void* d_ws, size_t ws_size,
                              hipStream_t stream) {
  const float* coords = (const float*)d_in[0];
  const float* feats  = (const float*)d_in[1];
  const float* W0 = (const float*)d_in[2];
  const float* g0 = (const float*)d_in[3];
  const float* b0 = (const float*)d_in[4];
  const float* W1 = (const float*)d_in[5];
  const float* g1 = (const float*)d_in[6];
  const float* b1 = (const float*)d_in[7];
  const float* Ws = (const float*)d_in[8];
  const float* gs = (const float*)d_in[9];
  const float* bs = (const float*)d_in[10];

  float* out_coords = (float*)d_out;
  float* out_feat   = out_coords + (size_t)Bn * Mn * 3;

  char* w = (char*)d_ws;
  float*    featsT = (float*)w;    w += (size_t)Bn * Nn * CIN * 4;   // 8 MB
  uint32_t* sidx   = (uint32_t*)w; w += (size_t)Bn * Mn * 4;
  uint32_t* gidx   = (uint32_t*)w; w += (size_t)Bn * Mn * Kn * 4;
  float*    wts    = (float*)w;    w += (size_t)Bn * Mn * Kn * 4;
  float*    ys     = (float*)w;    w += (size_t)Bn * Mn * COUT * 4;  // 4 MB
  unsigned short* accb = (unsigned short*)w; w += (size_t)2048 * 8192 * 2;  // 33.5 MB
  float*    stats  = (float*)w;    w += 1280 * 4;
  const bool cachemode = ws_size >= (size_t)(w - (char*)d_ws);

  hipMemsetAsync(stats, 0, 640 * 4, stream);
  hipLaunchKernelGGL(k_fused, dim3(520),  dim3(512), 0, stream,
                     coords, feats, featsT, sidx, out_coords);
  hipLaunchKernelGGL(k_knn,   dim3(8192), dim3(256), 0, stream, coords, sidx, gidx, wts);
  hipLaunchKernelGGL(k_conv1, dim3(2048), dim3(256), 0, stream,
                     coords, featsT, sidx, gidx, W0, stats,
                     cachemode ? accb : (unsigned short*)nullptr);
  hipLaunchKernelGGL(k_skip,  dim3(128),  dim3(256), 0, stream, featsT, sidx, Ws, ys, stats);
  if (cachemode) {
    hipLaunchKernelGGL(k_conv2c, dim3(2048), dim3(256), 0, stream, accb, W1, stats, g0, b0);
    hipLaunchKernelGGL(k_outc,   dim3(2048), dim3(256), 0, stream,
                       accb, W1, wts, ys, stats, g0, b0, g1, b1, gs, bs, out_feat);
  } else {
    hipLaunchKernelGGL(k_fin0,  dim3(1),    dim3(64),  0, stream, stats, g0, b0);
    hipLaunchKernelGGL(k_conv2, dim3(2048), dim3(256), 0, stream,
                       coords, featsT, sidx, gidx, W0, W1, stats);
    hipLaunchKernelGGL(k_fin1,  dim3(1),    dim3(128), 0, stream, stats, g1, b1, gs, bs);
    hipLaunchKernelGGL(k_out,   dim3(2048), dim3(256), 0, stream,
                       coords, featsT, sidx, gidx, W0, W1, wts, ys, stats, out_feat);
  }
}

// Round 9
// 1045.400 us; speedup vs baseline: 2.0388x; 1.0526x over previous
//
#include <hip/hip_runtime.h>
#include <hip/hip_bf16.h>
#include <cstdint>

#define DEV __device__ __forceinline__

// Problem constants (from setup_inputs)
constexpr int Bn   = 8;
constexpr int Nn   = 4096;
constexpr int Mn   = 1024;   // N / STRIDE
constexpr int Kn   = 32;     // NSAMPLE
constexpr int CIN  = 64;
constexpr int COUT = 128;

// ---------------------------------------------------------------------------
// FPS v4.1 (R6 structure + ballot-based index broadcast, no ds_bpermute).
// ---------------------------------------------------------------------------
DEV float wave_max_f32(float x) {
#if __has_builtin(__builtin_amdgcn_update_dpp)
#define FSTEP(CTRL, RMASK)                                                      \
  {                                                                             \
    int o = __builtin_amdgcn_update_dpp(0, __float_as_int(x), CTRL, RMASK, 0xf, \
                                        false);                                 \
    x = fmaxf(x, __int_as_float(o));                                            \
  }
  FSTEP(0x111, 0xf)  // row_shr:1
  FSTEP(0x112, 0xf)  // row_shr:2
  FSTEP(0x114, 0xf)  // row_shr:4
  FSTEP(0x118, 0xf)  // row_shr:8
  FSTEP(0x142, 0xa)  // row_bcast:15 rows 1,3
  FSTEP(0x143, 0xc)  // row_bcast:31 rows 2,3
#undef FSTEP
#else
  for (int off = 1; off < 64; off <<= 1) x = fmaxf(x, __shfl_xor(x, off, 64));
#endif
  return x;  // lane 63 holds the wave max
}

DEV unsigned long long grp8_max_u64(unsigned long long k) {
#if __has_builtin(__builtin_amdgcn_update_dpp)
#define USTEP(CTRL)                                                                    \
  {                                                                                    \
    unsigned int lo = (unsigned int)__builtin_amdgcn_update_dpp(                       \
        0, (int)(unsigned int)k, CTRL, 0xf, 0xf, false);                               \
    unsigned int hi = (unsigned int)__builtin_amdgcn_update_dpp(                       \
        0, (int)(unsigned int)(k >> 32), CTRL, 0xf, 0xf, false);                       \
    unsigned long long o = ((unsigned long long)hi << 32) | lo;                        \
    if (o > k) k = o;                                                                  \
  }
  USTEP(0x111)  // row_shr:1
  USTEP(0x112)  // row_shr:2
  USTEP(0x114)  // row_shr:4
#undef USTEP
#else
  for (int off = 1; off < 8; off <<= 1) {
    unsigned int lo = __shfl_xor((unsigned int)k, off, 64);
    unsigned int hi = __shfl_xor((unsigned int)(k >> 32), off, 64);
    unsigned long long o = ((unsigned long long)hi << 32) | lo;
    if (o > k) k = o;
  }
#endif
  return k;  // lane 7 of each row holds max of that row's lanes 0..7
}

DEV uint32_t fps_round8(const float v[8], int t, unsigned long long (*part)[8], int p) {
  float v4[4]; int j4[4];
#pragma unroll
  for (int i = 0; i < 4; ++i) {
    bool r = v[2 * i + 1] > v[2 * i];
    v4[i] = r ? v[2 * i + 1] : v[2 * i];
    j4[i] = r ? 2 * i + 1 : 2 * i;
  }
  float v2[2]; int j2[2];
#pragma unroll
  for (int i = 0; i < 2; ++i) {
    bool r = v4[2 * i + 1] > v4[2 * i];
    v2[i] = r ? v4[2 * i + 1] : v4[2 * i];
    j2[i] = r ? j4[2 * i + 1] : j4[2 * i];
  }
  bool rr = v2[1] > v2[0];
  float bv = rr ? v2[1] : v2[0];
  int bj = rr ? j2[1] : j2[0];

  // ballots of bj bits are independent of the DPP max chain -> scheduler
  // overlaps them; removes the ds_bpermute from the serial chain.
  unsigned long long mb0 = __ballot((bj & 1) != 0);
  unsigned long long mb1 = __ballot((bj & 2) != 0);
  unsigned long long mb2 = __ballot((bj & 4) != 0);
  float wl = wave_max_f32(bv);
  float wmax = __int_as_float(__builtin_amdgcn_readlane(__float_as_int(wl), 63));
  unsigned long long mask = __ballot(bv == wmax);
  int Ls = (int)__ffsll(mask) - 1;           // lowest lane with the max
  int bjw = (int)((mb0 >> Ls) & 1ull) | ((int)((mb1 >> Ls) & 1ull) << 1) |
            ((int)((mb2 >> Ls) & 1ull) << 2);
  uint32_t idx = 8u * (uint32_t)((t & ~63) + Ls) + (uint32_t)bjw;
  const int sl = p & 1;
  if ((t & 63) == 0)
    part[sl][t >> 6] = ((unsigned long long)__float_as_uint(wmax) << 12) |
                       (unsigned long long)(4095u - idx);
  __syncthreads();
  unsigned long long kk = part[sl][t & 7];
  kk = grp8_max_u64(kk);
  unsigned int lo = (unsigned int)__builtin_amdgcn_readlane((int)(unsigned int)kk, 7);
  return 4095u - (lo & 4095u);
}

// ---------------------------------------------------------------------------
// Fused kernel: blocks 0..7 = FPS; blocks 8..519 = feats transpose.
// ---------------------------------------------------------------------------
__global__ __launch_bounds__(512, 1) void k_fused(const float* __restrict__ coords,
                                                  const float* __restrict__ feats,
                                                  float* __restrict__ featsT,
                                                  uint32_t* __restrict__ sidx,
                                                  float* __restrict__ outc) {
  __shared__ __align__(16) char smraw[Nn * 16];   // sp[Nn] | tile[64][65]
  __shared__ unsigned long long part[2][8];
  __shared__ uint32_t farl[Mn];
  __shared__ float s_mean[4];
  const int t = threadIdx.x;

  if (blockIdx.x >= 8) {  // ---- transpose role ----
    float (*tile)[65] = (float(*)[65])smraw;
    int bid = blockIdx.x - 8;
    int b = bid >> 6, n0 = (bid & 63) * 64;
    int lane = t & 63, grp = t >> 6;  // 8 groups of 64
    for (int r = 0; r < 8; ++r) {
      int c = grp + r * 8;
      tile[c][lane] = feats[((size_t)b * 64 + c) * 4096 + n0 + lane];
    }
    __syncthreads();
    for (int r = 0; r < 8; ++r) {
      int n = grp + r * 8;
      featsT[((size_t)b * 4096 + n0 + n) * 64 + lane] = tile[lane][n];
    }
    return;
  }

  // ---- FPS role ----
  float4* sp = (float4*)smraw;
  const int b = blockIdx.x;
  const float* cb = coords + (size_t)b * Nn * 3;
  for (int i = t; i < Nn; i += 512)
    sp[i] = make_float4(cb[3 * i], cb[3 * i + 1], cb[3 * i + 2], 0.f);
  __syncthreads();
  if (t == 0) {  // sequential in-order fp32 mean (numpy reduce order; proven)
    float ax = 0.f, ay = 0.f, az = 0.f;
    for (int i = 0; i < Nn; ++i) {
      float4 c = sp[i];
      ax = __fadd_rn(ax, c.x); ay = __fadd_rn(ay, c.y); az = __fadd_rn(az, c.z);
    }
    s_mean[0] = __fdiv_rn(ax, 4096.f);
    s_mean[1] = __fdiv_rn(ay, 4096.f);
    s_mean[2] = __fdiv_rn(az, 4096.f);
  }
  __syncthreads();

  float px[8], py[8], pz[8], md[8];
#pragma unroll
  for (int j = 0; j < 8; ++j) {
    float4 c = sp[8 * t + j];                   // contiguous per thread
    px[j] = c.x; py[j] = c.y; pz[j] = c.z;
    md[j] = __builtin_inff();
  }

  uint32_t far;
  {
    float mx = s_mean[0], my = s_mean[1], mz = s_mean[2];
    float tv[8];
#pragma unroll
    for (int j = 0; j < 8; ++j) {
      float dx = __fsub_rn(px[j], mx), dy = __fsub_rn(py[j], my), dz = __fsub_rn(pz[j], mz);
      tv[j] = __fadd_rn(__fadd_rn(__fmul_rn(dx, dx), __fmul_rn(dy, dy)), __fmul_rn(dz, dz));
    }
    far = fps_round8(tv, t, part, 0);
  }

  for (int p = 1; p < Mn; ++p) {
    if (t == 0) farl[p - 1] = far;
    float4 c = sp[far];
#pragma unroll
    for (int j = 0; j < 8; ++j) {
      float dx = __fsub_rn(px[j], c.x), dy = __fsub_rn(py[j], c.y), dz = __fsub_rn(pz[j], c.z);
      float d = __fadd_rn(__fadd_rn(__fmul_rn(dx, dx), __fmul_rn(dy, dy)), __fmul_rn(dz, dz));
      md[j] = fminf(md[j], d);
    }
    far = fps_round8(md, t, part, p);
  }
  if (t == 0) farl[Mn - 1] = far;
  __syncthreads();

  for (int i = t; i < Mn; i += 512) {
    uint32_t f = farl[i];
    sidx[b * Mn + i] = f;
    float4 c = sp[f];
    outc[(size_t)(b * Mn + i) * 3 + 0] = c.x;
    outc[(size_t)(b * Mn + i) * 3 + 1] = c.y;
    outc[(size_t)(b * Mn + i) * 3 + 2] = c.z;
  }
}

// ---------------------------------------------------------------------------
// 32-NN per query (== reference ball_query+knn fallback) + density weights.
// ---------------------------------------------------------------------------
__global__ __launch_bounds__(256) void k_knn(const float* __restrict__ coords,
                                             const uint32_t* __restrict__ sidx,
                                             uint32_t* __restrict__ gidx,
                                             float* __restrict__ wts) {
  const int q = blockIdx.x;
  const int b = q >> 10;
  const int t = threadIdx.x;
  __shared__ unsigned long long keys[Nn + 2];
  __shared__ int s_cnt;
  __shared__ float s_q[4];
  __shared__ uint32_t s_sel[32];
  __shared__ float gx[32], gy[32], gz[32], g2[32];
  __shared__ float dmat[32 * 33];
  __shared__ float kth[32];
  __shared__ float s_raw[32];
  __shared__ float s_sum;

  if (t == 0) {
    uint32_t si = sidx[q];
    const float* c = &coords[((size_t)b * Nn + si) * 3];
    s_q[0] = c[0]; s_q[1] = c[1]; s_q[2] = c[2];
  }
  __syncthreads();
  float qx = s_q[0], qy = s_q[1], qz = s_q[2];
  float q2 = __fadd_rn(__fadd_rn(__fmul_rn(qx, qx), __fmul_rn(qy, qy)), __fmul_rn(qz, qz));
  const float* cb = coords + (size_t)b * Nn * 3;

  float thr = 0.04f;
  int cnt = 0;
  while (true) {
    if (t == 0) s_cnt = 0;
    __syncthreads();
    for (int j = 0; j < 16; ++j) {
      int i = t + 256 * j;
      float cx = cb[3 * i], cy = cb[3 * i + 1], cz = cb[3 * i + 2];
      float c2  = __fadd_rn(__fadd_rn(__fmul_rn(cx, cx), __fmul_rn(cy, cy)), __fmul_rn(cz, cz));
      float dot = __fadd_rn(__fadd_rn(__fmul_rn(qx, cx), __fmul_rn(qy, cy)), __fmul_rn(qz, cz));
      float d2  = __fsub_rn(__fadd_rn(q2, c2), __fmul_rn(2.f, dot));
      float d2c = fmaxf(d2, 1e-12f);
      bool pred = (d2c <= thr);
      unsigned long long mk = __ballot(pred);
      int base = 0;
      if ((t & 63) == 0 && mk) base = atomicAdd(&s_cnt, (int)__popcll(mk));
      base = __shfl(base, 0, 64);
      if (pred) {
        int pos = base + (int)__popcll(mk & ((1ull << (t & 63)) - 1ull));
        keys[pos] = ((unsigned long long)__float_as_uint(d2c) << 32) | (uint32_t)i;
      }
    }
    __syncthreads();
    cnt = s_cnt;
    if (cnt >= 32 || thr > 1.f) break;
    thr = (thr < 0.1f) ? 0.16f : 8.f;
    __syncthreads();
  }
  if (t == 0) { keys[cnt] = ~0ull; keys[cnt + 1] = ~0ull; }
  __syncthreads();
  int cnt2 = (cnt + 1) & ~1;
  for (int i = t; i < cnt; i += 256) {
    unsigned long long ki = keys[i];
    int r = 0;
    for (int j2 = 0; j2 < cnt2; j2 += 2) {
      unsigned long long a = keys[j2], c2 = keys[j2 + 1];
      r += (a < ki) + (c2 < ki);
    }
    if (r < 32) s_sel[r] = (uint32_t)ki;
  }
  __syncthreads();

  if (t < 32) {
    uint32_t gi = s_sel[t];
    gidx[(size_t)q * 32 + t] = gi;
    const float* c = &coords[((size_t)b * Nn + gi) * 3];
    float x = c[0], y = c[1], z = c[2];
    gx[t] = x; gy[t] = y; gz[t] = z;
    g2[t] = __fadd_rn(__fadd_rn(__fmul_rn(x, x), __fmul_rn(y, y)), __fmul_rn(z, z));
  }
  __syncthreads();
  for (int p = t; p < 1024; p += 256) {
    int i = p >> 5, jj = p & 31;
    float dot = __fadd_rn(__fadd_rn(__fmul_rn(gx[i], gx[jj]), __fmul_rn(gy[i], gy[jj])),
                          __fmul_rn(gz[i], gz[jj]));
    float d2 = __fsub_rn(__fadd_rn(g2[i], g2[jj]), __fmul_rn(2.f, dot));
    float dd = sqrtf(fmaxf(d2, 1e-12f));
    if (i == jj) dd = __builtin_inff();
    dmat[i * 33 + jj] = dd;
  }
  __syncthreads();
  for (int p = t; p < 1024; p += 256) {
    int i = p >> 5, jj = p & 31;
    float v = dmat[i * 33 + jj];
    int r = 0;
    for (int c = 0; c < 32; ++c) {
      float u = dmat[i * 33 + c];
      r += (u < v) || (u == v && c < jj);
    }
    if (r == 15) kth[i] = v;
  }
  __syncthreads();
  if (t < 32) { float x = fmaxf(kth[t], 1e-8f); s_raw[t] = x * x * x; }
  __syncthreads();
  if (t == 0) {
    float s = 0.f;
    for (int i2 = 0; i2 < 32; ++i2) s += s_raw[i2];
    s_sum = fmaxf(s, 1e-8f);
  }
  __syncthreads();
  if (t < 32) wts[(size_t)q * 32 + t] = s_raw[t] / s_sum;
}

// ---------------------------------------------------------------------------
// Conv pipeline. Tile = 4 queries x 32 neighbors (GEMM k-dim = 128).
// ---------------------------------------------------------------------------
constexpr int XST = 132;
constexpr int WST = 68;

DEV void build_x(const float* __restrict__ coords, const float* __restrict__ featsT,
                 const uint32_t* __restrict__ sidx, const uint32_t* __restrict__ gidx,
                 const float* __restrict__ W0, int b, int m0, int t,
                 float* xs, float* w0sT, uint32_t* s_gi, float* s_qc) {
  for (int i = t; i < 64 * 67; i += 256) {
    int o = i / 67, c = i - o * 67;
    w0sT[c * WST + o] = W0[i];
  }
  if (t < 128) {
    s_gi[t] = gidx[((size_t)(b * Mn + m0)) * 32 + t];
  } else if (t < 132) {
    int mm = t - 128;
    uint32_t si = sidx[b * Mn + m0 + mm];
    const float* c = &coords[((size_t)b * Nn + si) * 3];
    s_qc[mm * 3 + 0] = c[0]; s_qc[mm * 3 + 1] = c[1]; s_qc[mm * 3 + 2] = c[2];
  }
  __syncthreads();
  if (t < 128) {
    int mm = t >> 5;
    const float* c = &coords[((size_t)b * Nn + s_gi[t]) * 3];
    xs[0 * XST + t] = (c[0] - s_qc[mm * 3 + 0]) / 0.2f;
    xs[1 * XST + t] = (c[1] - s_qc[mm * 3 + 1]) / 0.2f;
    xs[2 * XST + t] = (c[2] - s_qc[mm * 3 + 2]) / 0.2f;
  }
  {
    int c = t & 63, k0g = t >> 6;
    for (int r2 = 0; r2 < 32; ++r2) {
      int kk = k0g + 4 * r2;
      xs[(size_t)(3 + c) * XST + kk] = featsT[((size_t)b * Nn + s_gi[kk]) * 64 + c];
    }
  }
  __syncthreads();
}

DEV void conv1_acc(const float* xs, const float* w0sT, int o0, int k0, float acc[32]) {
#pragma unroll
  for (int i = 0; i < 32; ++i) acc[i] = 0.f;
  for (int c = 0; c < 67; ++c) {
    float4 w  = *(const float4*)&w0sT[c * WST + o0];
    float4 xa = *(const float4*)&xs[c * XST + k0];
    float4 xb = *(const float4*)&xs[c * XST + k0 + 4];
    float wv[4] = {w.x, w.y, w.z, w.w};
    float xv[8] = {xa.x, xa.y, xa.z, xa.w, xb.x, xb.y, xb.z, xb.w};
#pragma unroll
    for (int i = 0; i < 4; ++i)
#pragma unroll
      for (int j = 0; j < 8; ++j)
        acc[i * 8 + j] = fmaf(wv[i], xv[j], acc[i * 8 + j]);
  }
}

DEV void conv2_acc(const float* hs, const float* w1sT, int o0, int k0, float acc2[32]) {
#pragma unroll
  for (int i = 0; i < 32; ++i) acc2[i] = 0.f;
  for (int c = 0; c < 64; ++c) {
    float4 w  = *(const float4*)&w1sT[c * WST + o0];
    float4 xa = *(const float4*)&hs[c * XST + k0];
    float4 xb = *(const float4*)&hs[c * XST + k0 + 4];
    float wv[4] = {w.x, w.y, w.z, w.w};
    float xv[8] = {xa.x, xa.y, xa.z, xa.w, xb.x, xb.y, xb.z, xb.w};
#pragma unroll
    for (int i = 0; i < 4; ++i)
#pragma unroll
      for (int j = 0; j < 8; ++j)
        acc2[i * 8 + j] = fmaf(wv[i], xv[j], acc2[i * 8 + j]);
  }
}

DEV unsigned short f2bf(float x) {
  __hip_bfloat16 h = __float2bfloat16(x);
  return *reinterpret_cast<unsigned short*>(&h);
}

// stats layout (floats): [0,64) s0 | [64,128) q0 | [128,256) s1 | [256,384) q1
// | [384,512) ss | [512,640) qs | 640 a0 | 704 c0 | 768 a1 | 896 c1
// | 1024 as | 1152 cs   (640+ used only by fallback path)

// ---- merged conv1 (+bf16 acc cache) and skip GEMM; skip role = blocks 2048+ ----
__global__ __launch_bounds__(256) void k_conv1s(const float* __restrict__ coords,
                                                const float* __restrict__ featsT,
                                                const uint32_t* __restrict__ sidx,
                                                const uint32_t* __restrict__ gidx,
                                                const float* __restrict__ W0,
                                                const float* __restrict__ Ws,
                                                float* __restrict__ ys,
                                                float* __restrict__ stats,
                                                unsigned short* __restrict__ accb) {
  __shared__ float smU[13400];
  __shared__ uint32_t s_gi[128];
  __shared__ float s_qc[12];
  __shared__ float ssum[128], ssq[128];
  int t = threadIdx.x;

  if (blockIdx.x >= 2048) {  // ---- skip role ----
    float* fin  = smU;              // [64][65]
    float* wssT = smU + 64 * 65;    // [64][129]
    uint32_t* s_si = s_gi;          // reuse (needs 64)
    int blk = blockIdx.x - 2048;
    int b = blk >> 4, m0 = (blk & 15) * 64;
    if (t < 64) s_si[t] = sidx[b * Mn + m0 + t];
    if (t < 128) { ssum[t] = 0.f; ssq[t] = 0.f; }
    __syncthreads();
    for (int i = t; i < 64 * 64; i += 256) {
      int mm = i >> 6, c = i & 63;
      fin[mm * 65 + c] = featsT[((size_t)b * Nn + s_si[mm]) * 64 + c];
    }
    for (int i = t; i < 128 * 64; i += 256) {
      int oo = i >> 6, cc = i & 63;
      wssT[cc * 129 + oo] = Ws[(size_t)oo * 64 + cc];
    }
    __syncthreads();
    int o = t & 127, mh = t >> 7;
    float s = 0.f, sq = 0.f;
    for (int mm = mh * 32; mm < mh * 32 + 32; ++mm) {
      float acc = 0.f;
      for (int c = 0; c < 64; ++c) acc = fmaf(wssT[c * 129 + o], fin[mm * 65 + c], acc);
      ys[((size_t)(b * Mn + m0 + mm)) * 128 + o] = acc;
      s += acc; sq = fmaf(acc, acc, sq);
    }
    atomicAdd(&ssum[o], s); atomicAdd(&ssq[o], sq);
    __syncthreads();
    if (t < 128) { atomicAdd(&stats[384 + t], ssum[t]); atomicAdd(&stats[512 + t], ssq[t]); }
    return;
  }

  // ---- conv1 role ----
  float* xs = smU; float* w0sT = smU + 67 * XST;
  int blk = blockIdx.x;
  int b = blk >> 8, m0 = (blk & 255) << 2;
  if (t < 64) { ssum[t] = 0.f; ssq[t] = 0.f; }
  build_x(coords, featsT, sidx, gidx, W0, b, m0, t, xs, w0sT, s_gi, s_qc);
  int o0 = (t & 15) * 4, k0 = (t >> 4) * 8;
  float acc[32];
  conv1_acc(xs, w0sT, o0, k0, acc);
  if (accb != nullptr) {  // cache pre-BN conv1 output as bf16 (RNE)
    unsigned short* at = accb + (size_t)blk * 8192;
#pragma unroll
    for (int i = 0; i < 4; ++i) {
      unsigned int w[4];
#pragma unroll
      for (int q = 0; q < 4; ++q)
        w[q] = (unsigned int)f2bf(acc[i * 8 + 2 * q]) |
               ((unsigned int)f2bf(acc[i * 8 + 2 * q + 1]) << 16);
      *(uint4*)&at[(o0 + i) * 128 + k0] = make_uint4(w[0], w[1], w[2], w[3]);
    }
  }
#pragma unroll
  for (int i = 0; i < 4; ++i) {
    float s = 0.f, sq = 0.f;
#pragma unroll
    for (int j = 0; j < 8; ++j) { s += acc[i * 8 + j]; sq = fmaf(acc[i * 8 + j], acc[i * 8 + j], sq); }
    atomicAdd(&ssum[o0 + i], s); atomicAdd(&ssq[o0 + i], sq);
  }
  __syncthreads();
  if (t < 64) { atomicAdd(&stats[t], ssum[t]); atomicAdd(&stats[64 + t], ssq[t]); }
}

// ---- cached-path conv2: read bf16 acc, in-kernel fin0; optional acc2 cache ----
__global__ __launch_bounds__(256) void k_conv2c(const unsigned short* __restrict__ accb,
                                                const float* __restrict__ W1,
                                                float* __restrict__ stats,
                                                const float* __restrict__ g0,
                                                const float* __restrict__ b0,
                                                unsigned short* __restrict__ acc2b) {
  __shared__ float hs[64 * XST];
  __shared__ float w1sT[64 * WST];
  __shared__ float s_a0[64], s_c0[64];
  __shared__ float ssum[128], ssq[128];
  int blk = blockIdx.x, t = threadIdx.x;
  if (t < 128) { ssum[t] = 0.f; ssq[t] = 0.f; }
  if (t < 64) {
    float mu  = stats[t] * (1.f / 262144.f);
    float var = stats[64 + t] * (1.f / 262144.f) - mu * mu;
    float a = g0[t] / sqrtf(var + 1e-5f);
    s_a0[t] = a; s_c0[t] = b0[t] - mu * a;
  }
  const unsigned short* at = accb + (size_t)blk * 8192;
  int o = t >> 2, kb = (t & 3) * 32;
  __syncthreads();
  float a0 = s_a0[o], c0 = s_c0[o];
#pragma unroll
  for (int g = 0; g < 4; ++g) {
    uint4 v = *(const uint4*)&at[o * 128 + kb + 8 * g];
    unsigned int vv[4] = {v.x, v.y, v.z, v.w};
#pragma unroll
    for (int q = 0; q < 4; ++q) {
      float f0 = __uint_as_float((vv[q] & 0xffffu) << 16);
      float f1 = __uint_as_float(vv[q] & 0xffff0000u);
      hs[o * XST + kb + 8 * g + 2 * q]     = fmaxf(fmaf(a0, f0, c0), 0.f);
      hs[o * XST + kb + 8 * g + 2 * q + 1] = fmaxf(fmaf(a0, f1, c0), 0.f);
    }
  }
  int o0 = (t & 15) * 4, k0 = (t >> 4) * 8;
  unsigned short* at2 = (acc2b != nullptr) ? acc2b + (size_t)blk * 16384 : nullptr;
  for (int p = 0; p < 2; ++p) {
    __syncthreads();
    for (int i = t; i < 64 * 64; i += 256) {
      int oo = i >> 6, cc = i & 63;
      w1sT[cc * WST + oo] = W1[(size_t)(64 * p + oo) * 64 + cc];
    }
    __syncthreads();
    float acc2[32];
    conv2_acc(hs, w1sT, o0, k0, acc2);
    if (at2 != nullptr) {  // store pre-BN conv2 output transposed [k][o2] bf16
#pragma unroll
      for (int j = 0; j < 8; ++j) {
        unsigned int lo = (unsigned int)f2bf(acc2[0 * 8 + j]) |
                          ((unsigned int)f2bf(acc2[1 * 8 + j]) << 16);
        unsigned int hi = (unsigned int)f2bf(acc2[2 * 8 + j]) |
                          ((unsigned int)f2bf(acc2[3 * 8 + j]) << 16);
        *(uint2*)&at2[(size_t)(k0 + j) * 128 + 64 * p + o0] = make_uint2(lo, hi);
      }
    }
#pragma unroll
    for (int i = 0; i < 4; ++i) {
      float s = 0.f, sq = 0.f;
#pragma unroll
      for (int j = 0; j < 8; ++j) { s += acc2[i * 8 + j]; sq = fmaf(acc2[i * 8 + j], acc2[i * 8 + j], sq); }
      atomicAdd(&ssum[64 * p + o0 + i], s); atomicAdd(&ssq[64 * p + o0 + i], sq);
    }
  }
  __syncthreads();
  if (t < 128) { atomicAdd(&stats[128 + t], ssum[t]); atomicAdd(&stats[256 + t], ssq[t]); }
}

// ---- tier-A output: thin reduce over cached bf16 conv2 output ----
__global__ __launch_bounds__(256) void k_outc2(const unsigned short* __restrict__ acc2b,
                                               const float* __restrict__ wts,
                                               const float* __restrict__ ys,
                                               const float* __restrict__ stats,
                                               const float* __restrict__ g1,
                                               const float* __restrict__ b1,
                                               const float* __restrict__ gs,
                                               const float* __restrict__ bs,
                                               float* __restrict__ out_feat) {
  __shared__ float s_a1[128], s_c1[128], s_as[128], s_cs[128];
  __shared__ float sw[4 * 36];
  __shared__ float red[128 * 5];
  int blk = blockIdx.x, t = threadIdx.x;
  int b = blk >> 8, m0 = (blk & 255) << 2;
  if (t < 128) {
    float mu  = stats[128 + t] * (1.f / 262144.f);
    float var = stats[256 + t] * (1.f / 262144.f) - mu * mu;
    float a = g1[t] / sqrtf(var + 1e-5f);
    s_a1[t] = a; s_c1[t] = b1[t] - mu * a;
    float mus  = stats[384 + t] * (1.f / 8192.f);
    float vars = stats[512 + t] * (1.f / 8192.f) - mus * mus;
    float as = gs[t] / sqrtf(vars + 1e-5f);
    s_as[t] = as; s_cs[t] = bs[t] - mus * as;
    sw[(t >> 5) * 36 + (t & 31)] = wts[((size_t)(b * Mn + m0)) * 32 + t];
  }
  __syncthreads();
  int o2 = t & 127, mh = t >> 7;
  float a1 = s_a1[o2], c1 = s_c1[o2], as = s_as[o2], cs = s_cs[o2];
  const unsigned short* base = acc2b + (size_t)blk * 16384;
#pragma unroll
  for (int mi = 0; mi < 2; ++mi) {
    int m = mh * 2 + mi;
    const unsigned short* col = base + (size_t)(m * 32) * 128 + o2;
    const float* swr = &sw[m * 36];
    float r = 0.f;
#pragma unroll
    for (int k = 0; k < 32; ++k) {
      float f = __uint_as_float((unsigned int)col[(size_t)k * 128] << 16);
      float msg = fmaxf(fmaf(a1, f, c1), 0.f);
      r = fmaf(msg, swr[k], r);
    }
    float ysv = ys[((size_t)(b * Mn + m0 + m)) * 128 + o2];
    red[o2 * 5 + m] = fmaxf(r + fmaf(as, ysv, cs), 0.f);
  }
  __syncthreads();
  for (int e = t; e < 512; e += 256) {
    int oo = e >> 2, mm = e & 3;
    out_feat[(size_t)b * 131072 + (size_t)oo * 1024 + m0 + mm] = red[oo * 5 + mm];
  }
}

// ---- tier-B output (R8 proven): recompute conv2 from accb ----
__global__ __launch_bounds__(256) void k_outc(const unsigned short* __restrict__ accb,
                                              const float* __restrict__ W1,
                                              const float* __restrict__ wts,
                                              const float* __restrict__ ys,
                                              const float* __restrict__ stats,
                                              const float* __restrict__ g0,
                                              const float* __restrict__ b0,
                                              const float* __restrict__ g1,
                                              const float* __restrict__ b1,
                                              const float* __restrict__ gs,
                                              const float* __restrict__ bs,
                                              float* __restrict__ out_feat) {
  __shared__ float hs[64 * XST];
  __shared__ float w1sT[64 * WST];
  __shared__ float s_a0[64], s_c0[64];
  __shared__ float s_a1[128], s_c1[128], s_as[128], s_cs[128];
  __shared__ __align__(16) float sw[4 * 36];
  __shared__ float red[128 * 5];
  int blk = blockIdx.x, t = threadIdx.x;
  int b = blk >> 8, m0 = (blk & 255) << 2;
  if (t < 64) {
    float mu  = stats[t] * (1.f / 262144.f);
    float var = stats[64 + t] * (1.f / 262144.f) - mu * mu;
    float a = g0[t] / sqrtf(var + 1e-5f);
    s_a0[t] = a; s_c0[t] = b0[t] - mu * a;
  }
  if (t < 128) {
    float mu  = stats[128 + t] * (1.f / 262144.f);
    float var = stats[256 + t] * (1.f / 262144.f) - mu * mu;
    float a = g1[t] / sqrtf(var + 1e-5f);
    s_a1[t] = a; s_c1[t] = b1[t] - mu * a;
    float mus  = stats[384 + t] * (1.f / 8192.f);
    float vars = stats[512 + t] * (1.f / 8192.f) - mus * mus;
    float as = gs[t] / sqrtf(vars + 1e-5f);
    s_as[t] = as; s_cs[t] = bs[t] - mus * as;
    sw[(t >> 5) * 36 + (t & 31)] = wts[((size_t)(b * Mn + m0)) * 32 + t];
  }
  const unsigned short* at = accb + (size_t)blk * 8192;
  int o = t >> 2, kb = (t & 3) * 32;
  __syncthreads();
  float a0 = s_a0[o], c0 = s_c0[o];
#pragma unroll
  for (int g = 0; g < 4; ++g) {
    uint4 v = *(const uint4*)&at[o * 128 + kb + 8 * g];
    unsigned int vv[4] = {v.x, v.y, v.z, v.w};
#pragma unroll
    for (int q = 0; q < 4; ++q) {
      float f0 = __uint_as_float((vv[q] & 0xffffu) << 16);
      float f1 = __uint_as_float(vv[q] & 0xffff0000u);
      hs[o * XST + kb + 8 * g + 2 * q]     = fmaxf(fmaf(a0, f0, c0), 0.f);
      hs[o * XST + kb + 8 * g + 2 * q + 1] = fmaxf(fmaf(a0, f1, c0), 0.f);
    }
  }
  int o0 = (t & 15) * 4, k0 = (t >> 4) * 8;
  int m = k0 >> 5, nb0 = k0 & 31;
  for (int p = 0; p < 2; ++p) {
    __syncthreads();
    for (int i = t; i < 64 * 64; i += 256) {
      int oo = i >> 6, cc = i & 63;
      w1sT[cc * WST + oo] = W1[(size_t)(64 * p + oo) * 64 + cc];
    }
    __syncthreads();
    float acc2[32];
    conv2_acc(hs, w1sT, o0, k0, acc2);
    float4 swa = *(const float4*)&sw[m * 36 + nb0];
    float4 swb = *(const float4*)&sw[m * 36 + nb0 + 4];
    float wv[8] = {swa.x, swa.y, swa.z, swa.w, swb.x, swb.y, swb.z, swb.w};
    float a1v[4], c1v[4];
#pragma unroll
    for (int i = 0; i < 4; ++i) { a1v[i] = s_a1[64 * p + o0 + i]; c1v[i] = s_c1[64 * p + o0 + i]; }
    float r4[4];
#pragma unroll
    for (int i = 0; i < 4; ++i) {
      float r = 0.f;
#pragma unroll
      for (int j = 0; j < 8; ++j) {
        float msg = fmaxf(fmaf(a1v[i], acc2[i * 8 + j], c1v[i]), 0.f);
        r = fmaf(msg, wv[j], r);
      }
      r4[i] = r;
    }
#pragma unroll
    for (int i = 0; i < 4; ++i) {
      float r = r4[i];
      r += __shfl_xor(r, 16, 64);
      r += __shfl_xor(r, 32, 64);
      r4[i] = r;
    }
    if ((t & 63) < 16) {
      float4 ysv = *(const float4*)&ys[((size_t)(b * Mn + m0 + m)) * 128 + 64 * p + o0];
      float yv[4] = {ysv.x, ysv.y, ysv.z, ysv.w};
#pragma unroll
      for (int i = 0; i < 4; ++i) {
        int o2 = 64 * p + o0 + i;
        red[o2 * 5 + m] = fmaxf(r4[i] + fmaf(s_as[o2], yv[i], s_cs[o2]), 0.f);
      }
    }
  }
  __syncthreads();
  for (int e = t; e < 512; e += 256) {
    int oo = e >> 2, mm = e & 3;
    out_feat[(size_t)b * 131072 + (size_t)oo * 1024 + m0 + mm] = red[oo * 5 + mm];
  }
}

// ---------------------------------------------------------------------------
// Tier-C fallback (no cache): R6 kernels
// ---------------------------------------------------------------------------
__global__ void k_fin0(float* stats, const float* g0, const float* b0) {
  int t = threadIdx.x;
  if (t >= 64) return;
  float mu  = stats[t] * (1.f / 262144.f);
  float var = stats[64 + t] * (1.f / 262144.f) - mu * mu;
  float a = g0[t] / sqrtf(var + 1e-5f);
  stats[640 + t] = a;
  stats[704 + t] = b0[t] - mu * a;
}

__global__ __launch_bounds__(256) void k_conv2(const float* __restrict__ coords,
                                               const float* __restrict__ featsT,
                                               const uint32_t* __restrict__ sidx,
                                               const uint32_t* __restrict__ gidx,
                                               const float* __restrict__ W0,
                                               const float* __restrict__ W1,
                                               float* __restrict__ stats) {
  __shared__ float smU[13400];
  __shared__ uint32_t s_gi[128];
  __shared__ float s_qc[12];
  __shared__ float ssum[128], ssq[128];
  float* xs = smU;  float* w0sT = smU + 67 * XST;
  float* hs = smU;  float* w1sT = smU + 64 * XST;
  int blk = blockIdx.x, t = threadIdx.x;
  int b = blk >> 8, m0 = (blk & 255) << 2;
  if (t < 128) { ssum[t] = 0.f; ssq[t] = 0.f; }
  build_x(coords, featsT, sidx, gidx, W0, b, m0, t, xs, w0sT, s_gi, s_qc);
  int o0 = (t & 15) * 4, k0 = (t >> 4) * 8;
  float acc[32];
  conv1_acc(xs, w0sT, o0, k0, acc);
  float4 a04 = *(const float4*)&stats[640 + o0];
  float4 c04 = *(const float4*)&stats[704 + o0];
  float a0v[4] = {a04.x, a04.y, a04.z, a04.w};
  float c0v[4] = {c04.x, c04.y, c04.z, c04.w};
  __syncthreads();
#pragma unroll
  for (int i = 0; i < 4; ++i) {
    float h[8];
#pragma unroll
    for (int j = 0; j < 8; ++j) h[j] = fmaxf(fmaf(a0v[i], acc[i * 8 + j], c0v[i]), 0.f);
    *(float4*)&hs[(o0 + i) * XST + k0]     = make_float4(h[0], h[1], h[2], h[3]);
    *(float4*)&hs[(o0 + i) * XST + k0 + 4] = make_float4(h[4], h[5], h[6], h[7]);
  }
  for (int p = 0; p < 2; ++p) {
    __syncthreads();
    for (int i = t; i < 64 * 64; i += 256) {
      int oo = i >> 6, cc = i & 63;
      w1sT[cc * WST + oo] = W1[(size_t)(64 * p + oo) * 64 + cc];
    }
    __syncthreads();
    float acc2[32];
    conv2_acc(hs, w1sT, o0, k0, acc2);
#pragma unroll
    for (int i = 0; i < 4; ++i) {
      float s = 0.f, sq = 0.f;
#pragma unroll
      for (int j = 0; j < 8; ++j) { s += acc2[i * 8 + j]; sq = fmaf(acc2[i * 8 + j], acc2[i * 8 + j], sq); }
      atomicAdd(&ssum[64 * p + o0 + i], s); atomicAdd(&ssq[64 * p + o0 + i], sq);
    }
  }
  __syncthreads();
  if (t < 128) { atomicAdd(&stats[128 + t], ssum[t]); atomicAdd(&stats[256 + t], ssq[t]); }
}

__global__ void k_fin1(float* stats, const float* g1, const float* b1,
                       const float* gs, const float* bs) {
  int t = threadIdx.x;
  if (t >= 128) return;
  float mu  = stats[128 + t] * (1.f / 262144.f);
  float var = stats[256 + t] * (1.f / 262144.f) - mu * mu;
  float a = g1[t] / sqrtf(var + 1e-5f);
  stats[768 + t] = a;
  stats[896 + t] = b1[t] - mu * a;
  float mus  = stats[384 + t] * (1.f / 8192.f);
  float vars = stats[512 + t] * (1.f / 8192.f) - mus * mus;
  float as = gs[t] / sqrtf(vars + 1e-5f);
  stats[1024 + t] = as;
  stats[1152 + t] = bs[t] - mus * as;
}

__global__ __launch_bounds__(256) void k_out(const float* __restrict__ coords,
                                             const float* __restrict__ featsT,
                                             const uint32_t* __restrict__ sidx,
                                             const uint32_t* __restrict__ gidx,
                                             const float* __restrict__ W0,
                                             const float* __restrict__ W1,
                                             const float* __restrict__ wts,
                                             const float* __restrict__ ys,
                                             const float* __restrict__ stats,
                                             float* __restrict__ out_feat) {
  __shared__ float smU[13400];
  __shared__ uint32_t s_gi[128];
  __shared__ float s_qc[12];
  __shared__ __align__(16) float sw[4 * 36];
  __shared__ float red[128 * 5];
  float* xs = smU;  float* w0sT = smU + 67 * XST;
  float* hs = smU;  float* w1sT = smU + 64 * XST;
  int blk = blockIdx.x, t = threadIdx.x;
  int b = blk >> 8, m0 = (blk & 255) << 2;
  build_x(coords, featsT, sidx, gidx, W0, b, m0, t, xs, w0sT, s_gi, s_qc);
  if (t < 128) sw[(t >> 5) * 36 + (t & 31)] = wts[((size_t)(b * Mn + m0)) * 32 + t];
  int o0 = (t & 15) * 4, k0 = (t >> 4) * 8;
  int m = k0 >> 5, nb0 = k0 & 31;
  float acc[32];
  conv1_acc(xs, w0sT, o0, k0, acc);
  float4 a04 = *(const float4*)&stats[640 + o0];
  float4 c04 = *(const float4*)&stats[704 + o0];
  float a0v[4] = {a04.x, a04.y, a04.z, a04.w};
  float c0v[4] = {c04.x, c04.y, c04.z, c04.w};
  __syncthreads();
#pragma unroll
  for (int i = 0; i < 4; ++i) {
    float h[8];
#pragma unroll
    for (int j = 0; j < 8; ++j) h[j] = fmaxf(fmaf(a0v[i], acc[i * 8 + j], c0v[i]), 0.f);
    *(float4*)&hs[(o0 + i) * XST + k0]     = make_float4(h[0], h[1], h[2], h[3]);
    *(float4*)&hs[(o0 + i) * XST + k0 + 4] = make_float4(h[4], h[5], h[6], h[7]);
  }
  for (int p = 0; p < 2; ++p) {
    __syncthreads();
    for (int i = t; i < 64 * 64; i += 256) {
      int oo = i >> 6, cc = i & 63;
      w1sT[cc * WST + oo] = W1[(size_t)(64 * p + oo) * 64 + cc];
    }
    __syncthreads();
    float acc2[32];
    conv2_acc(hs, w1sT, o0, k0, acc2);
    float4 swa = *(const float4*)&sw[m * 36 + nb0];
    float4 swb = *(const float4*)&sw[m * 36 + nb0 + 4];
    float wv[8] = {swa.x, swa.y, swa.z, swa.w, swb.x, swb.y, swb.z, swb.w};
    float4 a14 = *(const float4*)&stats[768 + 64 * p + o0];
    float4 c14 = *(const float4*)&stats[896 + 64 * p + o0];
    float a1v[4] = {a14.x, a14.y, a14.z, a14.w};
    float c1v[4] = {c14.x, c14.y, c14.z, c14.w};
    float r4[4];
#pragma unroll
    for (int i = 0; i < 4; ++i) {
      float r = 0.f;
#pragma unroll
      for (int j = 0; j < 8; ++j) {
        float msg = fmaxf(fmaf(a1v[i], acc2[i * 8 + j], c1v[i]), 0.f);
        r = fmaf(msg, wv[j], r);
      }
      r4[i] = r;
    }
#pragma unroll
    for (int i = 0; i < 4; ++i) {
      float r = r4[i];
      r += __shfl_xor(r, 16, 64);
      r += __shfl_xor(r, 32, 64);
      r4[i] = r;
    }
    if ((t & 63) < 16) {
      float4 ysv = *(const float4*)&ys[((size_t)(b * Mn + m0 + m)) * 128 + 64 * p + o0];
      float4 as4 = *(const float4*)&stats[1024 + 64 * p + o0];
      float4 cs4 = *(const float4*)&stats[1152 + 64 * p + o0];
      float yv[4] = {ysv.x, ysv.y, ysv.z, ysv.w};
      float av[4] = {as4.x, as4.y, as4.z, as4.w};
      float cv[4] = {cs4.x, cs4.y, cs4.z, cs4.w};
#pragma unroll
      for (int i = 0; i < 4; ++i)
        red[(64 * p + o0 + i) * 5 + m] = fmaxf(r4[i] + fmaf(av[i], yv[i], cv[i]), 0.f);
    }
  }
  __syncthreads();
  for (int e = t; e < 512; e += 256) {
    int oo = e >> 2, mm = e & 3;
    out_feat[(size_t)b * 131072 + (size_t)oo * 1024 + m0 + mm] = red[oo * 5 + mm];
  }
}

// ---------------------------------------------------------------------------
extern "C" void kernel_launch(void* const* d_in, const int* in_sizes, int n_in,
                              void* d_out, int out_size, void* d_ws, size_t ws_size,
                              hipStream_t stream) {
  const float* coords = (const float*)d_in[0];
  const float* feats  = (const float*)d_in[1];
  const float* W0 = (const float*)d_in[2];
  const float* g0 = (const float*)d_in[3];
  const float* b0 = (const float*)d_in[4];
  const float* W1 = (const float*)d_in[5];
  const float* g1 = (const float*)d_in[6];
  const float* b1 = (const float*)d_in[7];
  const float* Ws = (const float*)d_in[8];
  const float* gs = (const float*)d_in[9];
  const float* bs = (const float*)d_in[10];

  float* out_coords = (float*)d_out;
  float* out_feat   = out_coords + (size_t)Bn * Mn * 3;

  char* w = (char*)d_ws;
  float*    featsT = (float*)w;    w += (size_t)Bn * Nn * CIN * 4;   // 8 MB
  uint32_t* sidx   = (uint32_t*)w; w += (size_t)Bn * Mn * 4;
  uint32_t* gidx   = (uint32_t*)w; w += (size_t)Bn * Mn * Kn * 4;
  float*    wts    = (float*)w;    w += (size_t)Bn * Mn * Kn * 4;
  float*    ys     = (float*)w;    w += (size_t)Bn * Mn * COUT * 4;  // 4 MB
  unsigned short* accb = (unsigned short*)w; w += (size_t)2048 * 8192 * 2;  // 33.5 MB
  float*    stats  = (float*)w;    w += 1280 * 4;
  size_t needB = (size_t)(w - (char*)d_ws);
  unsigned short* acc2b = (unsigned short*)w; w += (size_t)2048 * 16384 * 2; // 67 MB
  size_t needA = (size_t)(w - (char*)d_ws);
  const bool tierA = ws_size >= needA;
  const bool tierB = ws_size >= needB;

  hipMemsetAsync(stats, 0, 640 * 4, stream);
  hipLaunchKernelGGL(k_fused, dim3(520),  dim3(512), 0, stream,
                     coords, feats, featsT, sidx, out_coords);
  hipLaunchKernelGGL(k_knn,   dim3(8192), dim3(256), 0, stream, coords, sidx, gidx, wts);
  hipLaunchKernelGGL(k_conv1s, dim3(2176), dim3(256), 0, stream,
                     coords, featsT, sidx, gidx, W0, Ws, ys, stats,
                     tierB ? accb : (unsigned short*)nullptr);
  if (tierA) {
    hipLaunchKernelGGL(k_conv2c, dim3(2048), dim3(256), 0, stream,
                       accb, W1, stats, g0, b0, acc2b);
    hipLaunchKernelGGL(k_outc2,  dim3(2048), dim3(256), 0, stream,
                       acc2b, wts, ys, stats, g1, b1, gs, bs, out_feat);
  } else if (tierB) {
    hipLaunchKernelGGL(k_conv2c, dim3(2048), dim3(256), 0, stream,
                       accb, W1, stats, g0, b0, (unsigned short*)nullptr);
    hipLaunchKernelGGL(k_outc,   dim3(2048), dim3(256), 0, stream,
                       accb, W1, wts, ys, stats, g0, b0, g1, b1, gs, bs, out_feat);
  } else {
    hipLaunchKernelGGL(k_fin0,  dim3(1),    dim3(64),  0, stream, stats, g0, b0);
    hipLaunchKernelGGL(k_conv2, dim3(2048), dim3(256), 0, stream,
                       coords, featsT, sidx, gidx, W0, W1, stats);
    hipLaunchKernelGGL(k_fin1,  dim3(1),    dim3(128), 0, stream, stats, g1, b1, gs, bs);
    hipLaunchKernelGGL(k_out,   dim3(2048), dim3(256), 0, stream,
                       coords, featsT, sidx, gidx, W0, W1, wts, ys, stats, out_feat);
  }
}